// Round 14
// baseline (3307.081 us; speedup 1.0000x reference)
//
#include <hip/hip_runtime.h>
#include <hip/hip_bf16.h>
#include <cstdint>
#include <cstddef>

// Problem constants
#define Bn 64
#define Pn 196
#define ENCn 2048
#define DECn 512
#define ATTn 512
#define En 300
#define Vn 30000
#define Tn 21
#define STEPSn 20
#define Gn 2048        // 4*DEC gate width
#define KIH 2348       // En + ENCn  (W_ih^T rows)
#define KWT 2860       // + DECn     (full WT incl. W_hh^T)

// ---- workspace layout (float offsets) ----
#define WS_ENCPROJ ((size_t)0)                            // bf16 enc_proj [12544][512] ushort; tail holds WCT; reused post-loop for Ah/Al
#define WS_WT    (WS_ENCPROJ + (size_t)Bn*Pn*ATTn)        // bf16 [2860][2048] ushort (fits: alloc 2348*2048 floats)
#define WS_CTX   (WS_WT + (size_t)KIH*Gn)                 // [64][2048] mean_f (pre only)
#define WS_H0    (WS_CTX + (size_t)Bn*ENCn)               // [64][512]
#define WS_C     (WS_H0 + (size_t)Bn*DECn)                // [64][512]
#define WS_HALL  (WS_C + (size_t)Bn*DECn)                 // [64][20][512]
#define WS_SCORES (WS_HALL + (size_t)Bn*STEPSn*DECn)      // [64][196]

// ---- output layout (float offsets into d_out) ----
#define OUT_ALPHAS ((size_t)Bn*STEPSn*Vn)
#define OUT_CAPT   (OUT_ALPHAS + (size_t)Bn*STEPSn*Pn)
#define OUT_SEQ    (OUT_CAPT + (size_t)Bn*Tn)
// During the loop, d_out's logits region holds Fih bf16 [12544][2048] (51.4 MB).

typedef __attribute__((ext_vector_type(8))) short short8;
typedef __attribute__((ext_vector_type(4))) short short4v;
typedef __attribute__((ext_vector_type(4))) float f32x4;

static __device__ __forceinline__ unsigned short f2bf(float f) {
    unsigned u = __float_as_uint(f);
    return (unsigned short)((u + 0x7FFFu + ((u >> 16) & 1u)) >> 16);
}
static __device__ __forceinline__ float bf2f(unsigned short u) {
    return __uint_as_float((unsigned)u << 16);
}

// ============ enc_proj via split-bf16 MFMA; bf16 output (verbatim R13) ============
__global__ __launch_bounds__(256) void k_encproj_mfma(
        const float* __restrict__ A,
        const float* __restrict__ B,
        const float* __restrict__ bias,
        unsigned short* __restrict__ Cbf) {
    __shared__ short Ah[128][40];
    __shared__ short Al[128][40];
    __shared__ short Bh[128][40];
    __shared__ short Bl[128][40];
    int m0 = blockIdx.x * 128, n0 = blockIdx.y * 128;
    int tid = threadIdx.x;
    int w = tid >> 6, l = tid & 63;
    int lr = l & 15, lk = (l >> 4) * 8;

    f32x4 acc[2][8];
    #pragma unroll
    for (int mt = 0; mt < 2; ++mt)
        #pragma unroll
        for (int nt = 0; nt < 8; ++nt) acc[mt][nt] = (f32x4){0.f, 0.f, 0.f, 0.f};

    for (int k0 = 0; k0 < ENCn; k0 += 32) {
        __syncthreads();
        #pragma unroll
        for (int i = 0; i < 2; ++i) {
            int q = tid + i * 256;
            int r = q >> 2, c8 = (q & 3) * 8;
            const float* src = A + (size_t)(m0 + r) * ENCn + k0 + c8;
            float4 v0 = *(const float4*)src;
            float4 v1 = *(const float4*)(src + 4);
            float vv[8] = {v0.x, v0.y, v0.z, v0.w, v1.x, v1.y, v1.z, v1.w};
            short8 h8, l8;
            #pragma unroll
            for (int j = 0; j < 8; ++j) {
                unsigned short hi = f2bf(vv[j]);
                float rem = vv[j] - __uint_as_float((unsigned)hi << 16);
                h8[j] = (short)hi;
                l8[j] = (short)f2bf(rem);
            }
            *(short8*)&Ah[r][c8] = h8;
            *(short8*)&Al[r][c8] = l8;
        }
        #pragma unroll
        for (int i = 0; i < 2; ++i) {
            int q = tid + i * 256;
            int n = q & 127, kc = (q >> 7) * 8;
            float vv[8];
            #pragma unroll
            for (int j = 0; j < 8; ++j)
                vv[j] = B[(size_t)(k0 + kc + j) * ATTn + n0 + n];
            short8 h8, l8;
            #pragma unroll
            for (int j = 0; j < 8; ++j) {
                unsigned short hi = f2bf(vv[j]);
                float rem = vv[j] - __uint_as_float((unsigned)hi << 16);
                h8[j] = (short)hi;
                l8[j] = (short)f2bf(rem);
            }
            *(short8*)&Bh[n][kc] = h8;
            *(short8*)&Bl[n][kc] = l8;
        }
        __syncthreads();
        short8 ah[2], al2[2];
        #pragma unroll
        for (int mt = 0; mt < 2; ++mt) {
            int row = w * 32 + mt * 16 + lr;
            ah[mt]  = *(const short8*)&Ah[row][lk];
            al2[mt] = *(const short8*)&Al[row][lk];
        }
        #pragma unroll
        for (int nt = 0; nt < 8; ++nt) {
            short8 bh = *(const short8*)&Bh[nt * 16 + lr][lk];
            short8 bl = *(const short8*)&Bl[nt * 16 + lr][lk];
            #pragma unroll
            for (int mt = 0; mt < 2; ++mt) {
                acc[mt][nt] = __builtin_amdgcn_mfma_f32_16x16x32_bf16(ah[mt], bh, acc[mt][nt], 0, 0, 0);
                acc[mt][nt] = __builtin_amdgcn_mfma_f32_16x16x32_bf16(ah[mt], bl, acc[mt][nt], 0, 0, 0);
                acc[mt][nt] = __builtin_amdgcn_mfma_f32_16x16x32_bf16(al2[mt], bh, acc[mt][nt], 0, 0, 0);
            }
        }
    }
    #pragma unroll
    for (int mt = 0; mt < 2; ++mt) {
        #pragma unroll
        for (int nt = 0; nt < 8; ++nt) {
            int n = n0 + nt * 16 + lr;
            float bv = bias[n];
            #pragma unroll
            for (int r = 0; r < 4; ++r) {
                int m = m0 + w * 32 + mt * 16 + (l >> 4) * 4 + r;
                Cbf[(size_t)m * ATTn + n] = f2bf(acc[mt][nt][r] + bv);
            }
        }
    }
}

// ============ Fih = features @ W_ih_ctx^T : split-A × bf16-B MFMA ============
// grid (98, 16); C tile 128x128; output bf16 [12544][2048] into d_out stash.
__global__ __launch_bounds__(256) void k_fih(const float* __restrict__ A,
                                             const unsigned short* __restrict__ WCT,
                                             unsigned short* __restrict__ Cbf) {
    __shared__ short Ah[128][40];
    __shared__ short Al[128][40];
    __shared__ short Bs[128][40];
    int m0 = blockIdx.x * 128, n0 = blockIdx.y * 128;
    int tid = threadIdx.x;
    int w = tid >> 6, l = tid & 63;
    int lr = l & 15, lk = (l >> 4) * 8;

    f32x4 acc[2][8];
    #pragma unroll
    for (int mt = 0; mt < 2; ++mt)
        #pragma unroll
        for (int nt = 0; nt < 8; ++nt) acc[mt][nt] = (f32x4){0.f, 0.f, 0.f, 0.f};

    for (int k0 = 0; k0 < ENCn; k0 += 32) {
        __syncthreads();
        #pragma unroll
        for (int i = 0; i < 2; ++i) {
            int q = tid + i * 256;
            int r = q >> 2, c8 = (q & 3) * 8;
            const float* src = A + (size_t)(m0 + r) * ENCn + k0 + c8;
            float4 v0 = *(const float4*)src;
            float4 v1 = *(const float4*)(src + 4);
            float vv[8] = {v0.x, v0.y, v0.z, v0.w, v1.x, v1.y, v1.z, v1.w};
            short8 h8, l8;
            #pragma unroll
            for (int j = 0; j < 8; ++j) {
                unsigned short hi = f2bf(vv[j]);
                float rem = vv[j] - __uint_as_float((unsigned)hi << 16);
                h8[j] = (short)hi;
                l8[j] = (short)f2bf(rem);
            }
            *(short8*)&Ah[r][c8] = h8;
            *(short8*)&Al[r][c8] = l8;
        }
        #pragma unroll
        for (int i = 0; i < 2; ++i) {
            int q = tid + i * 256;
            int n = q >> 2, kc = (q & 3) * 8;
            *(short8*)&Bs[n][kc] =
                *(const short8*)&WCT[(size_t)(n0 + n) * ENCn + k0 + kc];
        }
        __syncthreads();
        short8 ah[2], al2[2];
        #pragma unroll
        for (int mt = 0; mt < 2; ++mt) {
            int row = w * 32 + mt * 16 + lr;
            ah[mt]  = *(const short8*)&Ah[row][lk];
            al2[mt] = *(const short8*)&Al[row][lk];
        }
        #pragma unroll
        for (int nt = 0; nt < 8; ++nt) {
            short8 bs = *(const short8*)&Bs[nt * 16 + lr][lk];
            #pragma unroll
            for (int mt = 0; mt < 2; ++mt) {
                acc[mt][nt] = __builtin_amdgcn_mfma_f32_16x16x32_bf16(ah[mt], bs, acc[mt][nt], 0, 0, 0);
                acc[mt][nt] = __builtin_amdgcn_mfma_f32_16x16x32_bf16(al2[mt], bs, acc[mt][nt], 0, 0, 0);
            }
        }
    }
    #pragma unroll
    for (int mt = 0; mt < 2; ++mt) {
        #pragma unroll
        for (int nt = 0; nt < 8; ++nt) {
            int n = n0 + nt * 16 + lr;
            #pragma unroll
            for (int r = 0; r < 4; ++r) {
                int m = m0 + w * 32 + mt * 16 + (l >> 4) * 4 + r;
                Cbf[(size_t)m * Gn + n] = f2bf(acc[mt][nt][r]);
            }
        }
    }
}

// ================= small precompute kernels =================

// WCT[g][k] = bf16(W_ih[g][En+k])  (strided copy+convert; g-row contiguous)
__global__ __launch_bounds__(256) void k_wct(const float* __restrict__ W_ih,
                                             unsigned short* __restrict__ WCT) {
    int g = blockIdx.x;
    int k8 = threadIdx.x * 8;
    const float* src = W_ih + (size_t)g * KIH + En + k8;
    float4 v0 = *(const float4*)src;
    float4 v1 = *(const float4*)(src + 4);
    float vv[8] = {v0.x, v0.y, v0.z, v0.w, v1.x, v1.y, v1.z, v1.w};
    short8 o;
    #pragma unroll
    for (int j = 0; j < 8; ++j) o[j] = (short)f2bf(vv[j]);
    *(short8*)&WCT[(size_t)g * ENCn + k8] = o;
}

__global__ __launch_bounds__(256) void k_mean(const float* __restrict__ feat,
                                              float* __restrict__ mean_f) {
    int b = blockIdx.x;
    int e = blockIdx.y * 256 + threadIdx.x;
    const float* fb = feat + (size_t)b * Pn * ENCn + e;
    float s = 0.f;
    #pragma unroll 4
    for (int p = 0; p < Pn; ++p) s += fb[(size_t)p * ENCn];
    mean_f[(size_t)b * ENCn + e] = s * (1.0f / (float)Pn);
}

__global__ __launch_bounds__(256) void k_init_state(
        const float* __restrict__ mf,
        const float* __restrict__ Wh, const float* __restrict__ bh,
        const float* __restrict__ Wc, const float* __restrict__ bc,
        float* __restrict__ h, float* __restrict__ c) {
    int n = blockIdx.x * 256 + threadIdx.x;
    int b0 = blockIdx.y * 4;
    float ah[4], ac[4];
    float bhv = bh[n], bcv = bc[n];
    #pragma unroll
    for (int j = 0; j < 4; ++j) { ah[j] = bhv; ac[j] = bcv; }
    for (int k = 0; k < ENCn; ++k) {
        float wh = Wh[(size_t)k * DECn + n];
        float wc = Wc[(size_t)k * DECn + n];
        #pragma unroll
        for (int j = 0; j < 4; ++j) {
            float a = mf[(size_t)(b0 + j) * ENCn + k];
            ah[j] += a * wh;
            ac[j] += a * wc;
        }
    }
    #pragma unroll
    for (int j = 0; j < 4; ++j) {
        h[(size_t)(b0 + j) * DECn + n] = ah[j];
        c[(size_t)(b0 + j) * DECn + n] = ac[j];
    }
}

// transpose in[R][C] fp32 -> out[C][R] bf16 (row-stride R)
__global__ __launch_bounds__(256) void k_transpose_bf(const float* __restrict__ in,
                                                      unsigned short* __restrict__ out,
                                                      int R, int C) {
    __shared__ float tile[32][33];
    int c0 = blockIdx.x * 32, r0 = blockIdx.y * 32;
    int tx = threadIdx.x & 31, ty = threadIdx.x >> 5;
    for (int i = ty; i < 32; i += 8) {
        int r = r0 + i, cc = c0 + tx;
        tile[i][tx] = (r < R && cc < C) ? in[(size_t)r * C + cc] : 0.f;
    }
    __syncthreads();
    for (int i = ty; i < 32; i += 8) {
        int cc = c0 + i, r = r0 + tx;
        if (cc < C && r < R) out[(size_t)cc * R + r] = f2bf(tile[tx][i]);
    }
}

__global__ __launch_bounds__(256) void k_tail(const int* __restrict__ captions,
                                              const int* __restrict__ caption_len,
                                              float* __restrict__ out) {
    int i = blockIdx.x * 256 + threadIdx.x;
    if (i < Bn * Tn) {
        out[OUT_CAPT + i] = (float)captions[i];
    } else if (i < Bn * Tn + Bn) {
        int b = i - Bn * Tn;
        out[OUT_SEQ + b] = (float)(caption_len[b] - 1);
    }
}

// ================= per-step kernel A: hdec + raw scores (R13, cleaned) =================
__global__ __launch_bounds__(256) void k_scores(const unsigned short* __restrict__ enc_proj,
                                                const float* __restrict__ hbase, int hstride,
                                                const float* __restrict__ W_dec,
                                                const float* __restrict__ b_dec,
                                                const float* __restrict__ W_att,
                                                const float* __restrict__ b_att,
                                                float* __restrict__ scores) {
    __shared__ float hv[DECn];
    __shared__ float hs[ATTn];
    __shared__ float wa[ATTn];
    int bid = blockIdx.x;
    int b = bid >> 2, q = bid & 3;
    int tid = threadIdx.x;
    hv[tid]       = hbase[(size_t)b * hstride + tid];
    hv[tid + 256] = hbase[(size_t)b * hstride + tid + 256];
    wa[tid]       = W_att[tid];
    wa[tid + 256] = W_att[tid + 256];
    __syncthreads();
    {
        float acc0 = b_dec[tid], acc1 = b_dec[tid + 256];
        const float* wd = W_dec + tid;
        #pragma unroll 8
        for (int k = 0; k < DECn; ++k) {
            float h = hv[k];
            acc0 += h * wd[(size_t)k * DECn];
            acc1 += h * wd[(size_t)k * DECn + 256];
        }
        hs[tid] = acc0;
        hs[tid + 256] = acc1;
    }
    __syncthreads();
    int wv = tid >> 6, lane = tid & 63;
    float batt = b_att[0];
    for (int p = q * 49 + wv; p < q * 49 + 49; p += 4) {
        const unsigned short* ep = enc_proj + ((size_t)b * Pn + p) * ATTn;
        float s = 0.f;
        #pragma unroll
        for (int a = lane; a < ATTn; a += 64) {
            float v = bf2f(ep[a]) + hs[a];
            s += fmaxf(v, 0.f) * wa[a];
        }
        #pragma unroll
        for (int off = 32; off > 0; off >>= 1) s += __shfl_xor(s, off);
        if (lane == 0) scores[(size_t)b * Pn + p] = s + batt;
    }
}

// ================= per-step kernel B: softmax + gates + LSTM =================
// 512 blocks: b = bid>>3, ds = bid&7 (d-slice of 64; xcd = ds -> WT slices L2-hot).
// thread: gate = tid>>6, dd = tid&63; g = gate*512 + ds*64 + dd.
// gates = b_ih+b_hh + emb·WT[0:300] + sum_p alpha[p]*Fih[b,p,g] + h·WT[2348:2860].
__global__ __launch_bounds__(256) void k_gates2(const unsigned short* __restrict__ WT,
                                                const unsigned short* __restrict__ Fih,
                                                const float* __restrict__ emb,
                                                const int* __restrict__ captions,
                                                const float* __restrict__ scores,
                                                const float* __restrict__ hbase, int hstride,
                                                const float* __restrict__ b_ih,
                                                const float* __restrict__ b_hh,
                                                float* __restrict__ c,
                                                float* __restrict__ hall,
                                                float* __restrict__ alphas_out, int t) {
    __shared__ float al[Pn];
    __shared__ float red[4];
    __shared__ float Aemb[En];
    __shared__ float Ah2[DECn];
    __shared__ unsigned short Ftile[48][256];
    __shared__ float sg[4][64];
    int bid = blockIdx.x;
    int b = bid >> 3, ds = bid & 7;
    int tid = threadIdx.x;
    int gate = tid >> 6, dd = tid & 63;
    int g = (gate << 9) + ds * 64 + dd;

    // softmax (redundant per ds; R13 reduction order)
    int wv = tid >> 6, lane = tid & 63;
    float v = (tid < Pn) ? scores[(size_t)b * Pn + tid] : -1e30f;
    float m = v;
    #pragma unroll
    for (int off = 32; off > 0; off >>= 1) m = fmaxf(m, __shfl_xor(m, off));
    if (lane == 0) red[wv] = m;
    __syncthreads();
    float M = fmaxf(fmaxf(red[0], red[1]), fmaxf(red[2], red[3]));
    __syncthreads();
    float e = (tid < Pn) ? expf(v - M) : 0.f;
    float s = e;
    #pragma unroll
    for (int off = 32; off > 0; off >>= 1) s += __shfl_xor(s, off);
    if (lane == 0) red[wv] = s;
    __syncthreads();
    float S = red[0] + red[1] + red[2] + red[3];
    float an = e / S;
    if (tid < Pn) {
        al[tid] = an;
        if (ds == 0) alphas_out[((size_t)b * STEPSn + t) * Pn + tid] = an;
    }
    // stage emb + h
    const float* er = emb + (size_t)captions[b * Tn + t] * En;
    for (int k = tid; k < En; k += 256) Aemb[k] = er[k];
    for (int k = tid; k < DECn; k += 256) Ah2[k] = hbase[(size_t)b * hstride + k];
    __syncthreads();

    float acc = b_ih[g] + b_hh[g];
    // emb part
    #pragma unroll 4
    for (int k = 0; k < En; ++k)
        acc += Aemb[k] * bf2f(WT[(size_t)k * Gn + g]);
    // Fih part: 5 chunks (48,48,48,48,4)
    const unsigned short* fb = Fih + (size_t)b * Pn * Gn;
    int p0 = 0;
    for (int pc = 0; pc < 5; ++pc) {
        int rows = (pc < 4) ? 48 : 4;
        __syncthreads();
        for (int q = tid; q < rows * 32; q += 256) {
            int pr = q >> 5, j = q & 31;
            int seg = j >> 3, s8 = (j & 7) * 8;
            int col = (seg << 9) + ds * 64 + s8;
            *(short8*)&Ftile[pr][seg * 64 + s8] =
                *(const short8*)&fb[(size_t)(p0 + pr) * Gn + col];
        }
        __syncthreads();
        #pragma unroll 4
        for (int pr = 0; pr < rows; ++pr)
            acc += al[p0 + pr] * bf2f(Ftile[pr][tid]);
        p0 += rows;
    }
    // h part (real W_hh^T now)
    #pragma unroll 4
    for (int k = 0; k < DECn; ++k)
        acc += Ah2[k] * bf2f(WT[(size_t)(KIH + k) * Gn + g]);

    sg[gate][dd] = acc;
    __syncthreads();
    if (tid < 64) {
        float gi = sg[0][tid], gf = sg[1][tid];
        float gg = sg[2][tid], go = sg[3][tid];
        int d = ds * 64 + tid;
        float si = 1.f / (1.f + expf(-gi));
        float sf = 1.f / (1.f + expf(-gf));
        float so = 1.f / (1.f + expf(-go));
        size_t cidx = (size_t)b * DECn + d;
        float cc = sf * c[cidx] + si * tanhf(gg);
        float hh = so * tanhf(cc);
        c[cidx] = cc;
        hall[((size_t)b * STEPSn + t) * DECn + d] = hh;
    }
}

// ================= logits via split-bf16 MFMA =================

__global__ __launch_bounds__(256) void k_splitA(const float* __restrict__ hall,
                                                short* __restrict__ Ah,
                                                short* __restrict__ Al) {
    int idx = blockIdx.x * 256 + threadIdx.x;
    size_t base = (size_t)idx * 4;
    float4 v = *(const float4*)(hall + base);
    float a[4] = {v.x, v.y, v.z, v.w};
    short4v h, l;
    #pragma unroll
    for (int j = 0; j < 4; ++j) {
        unsigned short hi = f2bf(a[j]);
        float lo = a[j] - __uint_as_float((unsigned)hi << 16);
        h[j] = (short)hi;
        l[j] = (short)f2bf(lo);
    }
    *(short4v*)(Ah + base) = h;
    *(short4v*)(Al + base) = l;
}

__global__ __launch_bounds__(512) void k_logits_mfma(const short* __restrict__ Ah,
                                                     const short* __restrict__ Al,
                                                     const float* __restrict__ W_out,
                                                     const float* __restrict__ b_out,
                                                     float* __restrict__ out) {
    __shared__ short Bh[48][520];
    __shared__ short Bl[48][520];
    int n0 = blockIdx.x * 48;
    int tid = threadIdx.x;
    for (int q = tid; q < 6144; q += 512) {
        int cq = q % 12, k = q / 12;
        const float* src = W_out + (size_t)k * Vn + n0 + cq * 4;
        float4 v = *(const float4*)src;
        float a[4] = {v.x, v.y, v.z, v.w};
        #pragma unroll
        for (int j = 0; j < 4; ++j) {
            unsigned short hi = f2bf(a[j]);
            float lo = a[j] - __uint_as_float((unsigned)hi << 16);
            Bh[cq * 4 + j][k] = (short)hi;
            Bl[cq * 4 + j][k] = (short)f2bf(lo);
        }
    }
    __syncthreads();
    int w = tid >> 6, l = tid & 63;
    int lr = l & 15, lk = (l >> 4) * 8;
    float bias[3];
    #pragma unroll
    for (int nt = 0; nt < 3; ++nt) bias[nt] = b_out[n0 + nt * 16 + lr];

    for (int chunk = 0; chunk < 10; ++chunk) {
        int m0 = chunk * 128 + w * 16;
        f32x4 acc[3];
        #pragma unroll
        for (int nt = 0; nt < 3; ++nt) acc[nt] = (f32x4){0.f, 0.f, 0.f, 0.f};
        #pragma unroll 4
        for (int ks = 0; ks < 16; ++ks) {
            int k0 = ks * 32;
            short8 ah = *(const short8*)(Ah + (size_t)(m0 + lr) * DECn + k0 + lk);
            short8 al = *(const short8*)(Al + (size_t)(m0 + lr) * DECn + k0 + lk);
            #pragma unroll
            for (int nt = 0; nt < 3; ++nt) {
                short8 bh = *(const short8*)&Bh[nt * 16 + lr][k0 + lk];
                short8 bl = *(const short8*)&Bl[nt * 16 + lr][k0 + lk];
                acc[nt] = __builtin_amdgcn_mfma_f32_16x16x32_bf16(ah, bh, acc[nt], 0, 0, 0);
                acc[nt] = __builtin_amdgcn_mfma_f32_16x16x32_bf16(ah, bl, acc[nt], 0, 0, 0);
                acc[nt] = __builtin_amdgcn_mfma_f32_16x16x32_bf16(al, bh, acc[nt], 0, 0, 0);
            }
        }
        #pragma unroll
        for (int nt = 0; nt < 3; ++nt) {
            int n = n0 + nt * 16 + lr;
            #pragma unroll
            for (int r = 0; r < 4; ++r) {
                int m = m0 + (l >> 4) * 4 + r;
                out[(size_t)m * Vn + n] = acc[nt][r] + bias[nt];
            }
        }
    }
}

// ================= launcher =================

extern "C" void kernel_launch(void* const* d_in, const int* in_sizes, int n_in,
                              void* d_out, int out_size, void* d_ws, size_t ws_size,
                              hipStream_t stream) {
    const float* features    = (const float*)d_in[0];
    const int*   captions    = (const int*)d_in[1];
    const int*   caption_len = (const int*)d_in[2];
    const float* emb         = (const float*)d_in[3];
    const float* W_enc       = (const float*)d_in[4];
    const float* b_enc       = (const float*)d_in[5];
    const float* W_dec       = (const float*)d_in[6];
    const float* b_dec       = (const float*)d_in[7];
    const float* W_att       = (const float*)d_in[8];
    const float* b_att       = (const float*)d_in[9];
    const float* W_h0        = (const float*)d_in[10];
    const float* b_h0        = (const float*)d_in[11];
    const float* W_c0        = (const float*)d_in[12];
    const float* b_c0        = (const float*)d_in[13];
    const float* W_ih        = (const float*)d_in[14];
    const float* b_ih        = (const float*)d_in[15];
    const float* W_hh        = (const float*)d_in[16];
    const float* b_hh        = (const float*)d_in[17];
    const float* W_out       = (const float*)d_in[18];
    const float* b_out       = (const float*)d_in[19];

    float* out = (float*)d_out;
    float* ws  = (float*)d_ws;

    unsigned short* ws_encproj = (unsigned short*)(ws + WS_ENCPROJ);
    unsigned short* ws_wct     = ws_encproj + (size_t)Bn * Pn * ATTn;  // tail of encproj float region
    unsigned short* ws_WT      = (unsigned short*)(ws + WS_WT);        // [2860][2048] bf16
    float* ws_meanf   = ws + WS_CTX;
    float* ws_h0      = ws + WS_H0;
    float* ws_c       = ws + WS_C;
    float* ws_hall    = ws + WS_HALL;
    float* ws_scores  = ws + WS_SCORES;
    short* ws_Ah      = (short*)(ws + WS_ENCPROJ);       // reuse enc_proj region post-loop
    short* ws_Al      = ws_Ah + (size_t)Bn * STEPSn * DECn;
    unsigned short* fih = (unsigned short*)out;          // Fih stash in logits region

    // ---- precompute ----
    k_wct<<<dim3(Gn), 256, 0, stream>>>(W_ih, ws_wct);
    k_transpose_bf<<<dim3((KIH + 31) / 32, Gn / 32), 256, 0, stream>>>(
        W_ih, ws_WT, Gn, KIH);
    k_transpose_bf<<<dim3((DECn + 31) / 32, Gn / 32), 256, 0, stream>>>(
        W_hh, ws_WT + (size_t)KIH * Gn, Gn, DECn);       // THE FIX: real W_hh^T
    k_encproj_mfma<<<dim3(Pn * Bn / 128, ATTn / 128), 256, 0, stream>>>(
        features, W_enc, b_enc, ws_encproj);
    k_fih<<<dim3(Pn * Bn / 128, Gn / 128), 256, 0, stream>>>(features, ws_wct, fih);
    k_mean<<<dim3(Bn, ENCn / 256), 256, 0, stream>>>(features, ws_meanf);
    k_init_state<<<dim3(2, 16), 256, 0, stream>>>(ws_meanf, W_h0, b_h0, W_c0, b_c0,
                                                  ws_h0, ws_c);
    k_tail<<<dim3((Bn * Tn + Bn + 255) / 256), 256, 0, stream>>>(captions, caption_len, out);

    // ---- recurrence: 2 kernels per step ----
    for (int t = 0; t < STEPSn; ++t) {
        const float* hbase = (t == 0) ? ws_h0 : (ws_hall + (size_t)(t - 1) * DECn);
        int hstride = (t == 0) ? DECn : (STEPSn * DECn);
        k_scores<<<dim3(256), 256, 0, stream>>>(ws_encproj, hbase, hstride,
                                                W_dec, b_dec, W_att, b_att, ws_scores);
        k_gates2<<<dim3(512), 256, 0, stream>>>(ws_WT, fih, emb, captions, ws_scores,
                                                hbase, hstride, b_ih, b_hh,
                                                ws_c, ws_hall, out + OUT_ALPHAS, t);
    }

    // ---- logits: split A, then MFMA GEMM (overwrites Fih stash) ----
    k_splitA<<<dim3(Bn * STEPSn * DECn / 1024), 256, 0, stream>>>(ws_hall, ws_Ah, ws_Al);
    k_logits_mfma<<<dim3(Vn / 48), 512, 0, stream>>>(ws_Ah, ws_Al, W_out, b_out, out);
}

// Round 15
// 3083.562 us; speedup vs baseline: 1.0725x; 1.0725x over previous
//
#include <hip/hip_runtime.h>
#include <hip/hip_bf16.h>
#include <cstdint>
#include <cstddef>

// Problem constants
#define Bn 64
#define Pn 196
#define ENCn 2048
#define DECn 512
#define ATTn 512
#define En 300
#define Vn 30000
#define Tn 21
#define STEPSn 20
#define Gn 2048        // 4*DEC gate width
#define KIH 2348       // En + ENCn  (W_ih^T rows)

// ---- workspace layout (float offsets) ----
#define WS_ENCPROJ ((size_t)0)                            // bf16 enc_proj [12544][512] ushort; tail holds WCT; reused post-loop for Ah
#define WS_WT    (WS_ENCPROJ + (size_t)Bn*Pn*ATTn)        // bf16 [2860][2048] ushort
#define WS_CTX   (WS_WT + (size_t)KIH*Gn)                 // [64][2048] mean_f (pre only)
#define WS_H0    (WS_CTX + (size_t)Bn*ENCn)               // [64][512]
#define WS_C     (WS_H0 + (size_t)Bn*DECn)                // [64][512]
#define WS_HALL  (WS_C + (size_t)Bn*DECn)                 // [64][20][512]
#define WS_SCORES (WS_HALL + (size_t)Bn*STEPSn*DECn)      // [64][196]

// ---- output layout (float offsets into d_out) ----
#define OUT_ALPHAS ((size_t)Bn*STEPSn*Vn)
#define OUT_CAPT   (OUT_ALPHAS + (size_t)Bn*STEPSn*Pn)
#define OUT_SEQ    (OUT_CAPT + (size_t)Bn*Tn)
// During the loop, d_out's logits region holds Fih bf16 [12544][2048] (51.4 MB).

typedef __attribute__((ext_vector_type(8))) short short8;
typedef __attribute__((ext_vector_type(4))) short short4v;
typedef __attribute__((ext_vector_type(4))) float f32x4;

static __device__ __forceinline__ unsigned short f2bf(float f) {
    unsigned u = __float_as_uint(f);
    return (unsigned short)((u + 0x7FFFu + ((u >> 16) & 1u)) >> 16);
}
static __device__ __forceinline__ float bf2f(unsigned short u) {
    return __uint_as_float((unsigned)u << 16);
}

// ============ enc_proj via split-bf16 MFMA; bf16 output (verbatim R14) ============
__global__ __launch_bounds__(256) void k_encproj_mfma(
        const float* __restrict__ A,
        const float* __restrict__ B,
        const float* __restrict__ bias,
        unsigned short* __restrict__ Cbf) {
    __shared__ short Ah[128][40];
    __shared__ short Al[128][40];
    __shared__ short Bh[128][40];
    __shared__ short Bl[128][40];
    int m0 = blockIdx.x * 128, n0 = blockIdx.y * 128;
    int tid = threadIdx.x;
    int w = tid >> 6, l = tid & 63;
    int lr = l & 15, lk = (l >> 4) * 8;

    f32x4 acc[2][8];
    #pragma unroll
    for (int mt = 0; mt < 2; ++mt)
        #pragma unroll
        for (int nt = 0; nt < 8; ++nt) acc[mt][nt] = (f32x4){0.f, 0.f, 0.f, 0.f};

    for (int k0 = 0; k0 < ENCn; k0 += 32) {
        __syncthreads();
        #pragma unroll
        for (int i = 0; i < 2; ++i) {
            int q = tid + i * 256;
            int r = q >> 2, c8 = (q & 3) * 8;
            const float* src = A + (size_t)(m0 + r) * ENCn + k0 + c8;
            float4 v0 = *(const float4*)src;
            float4 v1 = *(const float4*)(src + 4);
            float vv[8] = {v0.x, v0.y, v0.z, v0.w, v1.x, v1.y, v1.z, v1.w};
            short8 h8, l8;
            #pragma unroll
            for (int j = 0; j < 8; ++j) {
                unsigned short hi = f2bf(vv[j]);
                float rem = vv[j] - __uint_as_float((unsigned)hi << 16);
                h8[j] = (short)hi;
                l8[j] = (short)f2bf(rem);
            }
            *(short8*)&Ah[r][c8] = h8;
            *(short8*)&Al[r][c8] = l8;
        }
        #pragma unroll
        for (int i = 0; i < 2; ++i) {
            int q = tid + i * 256;
            int n = q & 127, kc = (q >> 7) * 8;
            float vv[8];
            #pragma unroll
            for (int j = 0; j < 8; ++j)
                vv[j] = B[(size_t)(k0 + kc + j) * ATTn + n0 + n];
            short8 h8, l8;
            #pragma unroll
            for (int j = 0; j < 8; ++j) {
                unsigned short hi = f2bf(vv[j]);
                float rem = vv[j] - __uint_as_float((unsigned)hi << 16);
                h8[j] = (short)hi;
                l8[j] = (short)f2bf(rem);
            }
            *(short8*)&Bh[n][kc] = h8;
            *(short8*)&Bl[n][kc] = l8;
        }
        __syncthreads();
        short8 ah[2], al2[2];
        #pragma unroll
        for (int mt = 0; mt < 2; ++mt) {
            int row = w * 32 + mt * 16 + lr;
            ah[mt]  = *(const short8*)&Ah[row][lk];
            al2[mt] = *(const short8*)&Al[row][lk];
        }
        #pragma unroll
        for (int nt = 0; nt < 8; ++nt) {
            short8 bh = *(const short8*)&Bh[nt * 16 + lr][lk];
            short8 bl = *(const short8*)&Bl[nt * 16 + lr][lk];
            #pragma unroll
            for (int mt = 0; mt < 2; ++mt) {
                acc[mt][nt] = __builtin_amdgcn_mfma_f32_16x16x32_bf16(ah[mt], bh, acc[mt][nt], 0, 0, 0);
                acc[mt][nt] = __builtin_amdgcn_mfma_f32_16x16x32_bf16(ah[mt], bl, acc[mt][nt], 0, 0, 0);
                acc[mt][nt] = __builtin_amdgcn_mfma_f32_16x16x32_bf16(al2[mt], bh, acc[mt][nt], 0, 0, 0);
            }
        }
    }
    #pragma unroll
    for (int mt = 0; mt < 2; ++mt) {
        #pragma unroll
        for (int nt = 0; nt < 8; ++nt) {
            int n = n0 + nt * 16 + lr;
            float bv = bias[n];
            #pragma unroll
            for (int r = 0; r < 4; ++r) {
                int m = m0 + w * 32 + mt * 16 + (l >> 4) * 4 + r;
                Cbf[(size_t)m * ATTn + n] = f2bf(acc[mt][nt][r] + bv);
            }
        }
    }
}

// ============ Fih = features @ WCT^T : 1-pass bf16 MFMA ============
// grid (16, 98): x = n-tile (consecutive blocks share the A-panel -> L2/L3 hot),
// y = m-tile. 20.5 KB LDS -> high occupancy.
__global__ __launch_bounds__(256) void k_fih(const float* __restrict__ A,
                                             const unsigned short* __restrict__ WCT,
                                             unsigned short* __restrict__ Cbf) {
    __shared__ short Ahs[128][40];
    __shared__ short Bs[128][40];
    int n0 = blockIdx.x * 128, m0 = blockIdx.y * 128;
    int tid = threadIdx.x;
    int w = tid >> 6, l = tid & 63;
    int lr = l & 15, lk = (l >> 4) * 8;

    f32x4 acc[2][8];
    #pragma unroll
    for (int mt = 0; mt < 2; ++mt)
        #pragma unroll
        for (int nt = 0; nt < 8; ++nt) acc[mt][nt] = (f32x4){0.f, 0.f, 0.f, 0.f};

    for (int k0 = 0; k0 < ENCn; k0 += 32) {
        __syncthreads();
        #pragma unroll
        for (int i = 0; i < 2; ++i) {
            int q = tid + i * 256;
            int r = q >> 2, c8 = (q & 3) * 8;
            const float* src = A + (size_t)(m0 + r) * ENCn + k0 + c8;
            float4 v0 = *(const float4*)src;
            float4 v1 = *(const float4*)(src + 4);
            float vv[8] = {v0.x, v0.y, v0.z, v0.w, v1.x, v1.y, v1.z, v1.w};
            short8 h8;
            #pragma unroll
            for (int j = 0; j < 8; ++j) h8[j] = (short)f2bf(vv[j]);
            *(short8*)&Ahs[r][c8] = h8;
        }
        #pragma unroll
        for (int i = 0; i < 2; ++i) {
            int q = tid + i * 256;
            int n = q >> 2, kc = (q & 3) * 8;
            *(short8*)&Bs[n][kc] =
                *(const short8*)&WCT[(size_t)(n0 + n) * ENCn + k0 + kc];
        }
        __syncthreads();
        short8 ah[2];
        #pragma unroll
        for (int mt = 0; mt < 2; ++mt) {
            int row = w * 32 + mt * 16 + lr;
            ah[mt] = *(const short8*)&Ahs[row][lk];
        }
        #pragma unroll
        for (int nt = 0; nt < 8; ++nt) {
            short8 bs = *(const short8*)&Bs[nt * 16 + lr][lk];
            #pragma unroll
            for (int mt = 0; mt < 2; ++mt) {
                acc[mt][nt] = __builtin_amdgcn_mfma_f32_16x16x32_bf16(ah[mt], bs, acc[mt][nt], 0, 0, 0);
            }
        }
    }
    #pragma unroll
    for (int mt = 0; mt < 2; ++mt) {
        #pragma unroll
        for (int nt = 0; nt < 8; ++nt) {
            int n = n0 + nt * 16 + lr;
            #pragma unroll
            for (int r = 0; r < 4; ++r) {
                int m = m0 + w * 32 + mt * 16 + (l >> 4) * 4 + r;
                Cbf[(size_t)m * Gn + n] = f2bf(acc[mt][nt][r]);
            }
        }
    }
}

// ================= small precompute kernels =================

// WCT[g][k] = bf16(W_ih[g][En+k])
__global__ __launch_bounds__(256) void k_wct(const float* __restrict__ W_ih,
                                             unsigned short* __restrict__ WCT) {
    int g = blockIdx.x;
    int k8 = threadIdx.x * 8;
    const float* src = W_ih + (size_t)g * KIH + En + k8;
    float4 v0 = *(const float4*)src;
    float4 v1 = *(const float4*)(src + 4);
    float vv[8] = {v0.x, v0.y, v0.z, v0.w, v1.x, v1.y, v1.z, v1.w};
    short8 o;
    #pragma unroll
    for (int j = 0; j < 8; ++j) o[j] = (short)f2bf(vv[j]);
    *(short8*)&WCT[(size_t)g * ENCn + k8] = o;
}

__global__ __launch_bounds__(256) void k_mean(const float* __restrict__ feat,
                                              float* __restrict__ mean_f) {
    int b = blockIdx.x;
    int e = blockIdx.y * 256 + threadIdx.x;
    const float* fb = feat + (size_t)b * Pn * ENCn + e;
    float s = 0.f;
    #pragma unroll 4
    for (int p = 0; p < Pn; ++p) s += fb[(size_t)p * ENCn];
    mean_f[(size_t)b * ENCn + e] = s * (1.0f / (float)Pn);
}

__global__ __launch_bounds__(256) void k_init_state(
        const float* __restrict__ mf,
        const float* __restrict__ Wh, const float* __restrict__ bh,
        const float* __restrict__ Wc, const float* __restrict__ bc,
        float* __restrict__ h, float* __restrict__ c) {
    int n = blockIdx.x * 256 + threadIdx.x;
    int b0 = blockIdx.y * 4;
    float ah[4], ac[4];
    float bhv = bh[n], bcv = bc[n];
    #pragma unroll
    for (int j = 0; j < 4; ++j) { ah[j] = bhv; ac[j] = bcv; }
    for (int k = 0; k < ENCn; ++k) {
        float wh = Wh[(size_t)k * DECn + n];
        float wc = Wc[(size_t)k * DECn + n];
        #pragma unroll
        for (int j = 0; j < 4; ++j) {
            float a = mf[(size_t)(b0 + j) * ENCn + k];
            ah[j] += a * wh;
            ac[j] += a * wc;
        }
    }
    #pragma unroll
    for (int j = 0; j < 4; ++j) {
        h[(size_t)(b0 + j) * DECn + n] = ah[j];
        c[(size_t)(b0 + j) * DECn + n] = ac[j];
    }
}

// transpose in[R][C] fp32 -> out[C][R] bf16
__global__ __launch_bounds__(256) void k_transpose_bf(const float* __restrict__ in,
                                                      unsigned short* __restrict__ out,
                                                      int R, int C) {
    __shared__ float tile[32][33];
    int c0 = blockIdx.x * 32, r0 = blockIdx.y * 32;
    int tx = threadIdx.x & 31, ty = threadIdx.x >> 5;
    for (int i = ty; i < 32; i += 8) {
        int r = r0 + i, cc = c0 + tx;
        tile[i][tx] = (r < R && cc < C) ? in[(size_t)r * C + cc] : 0.f;
    }
    __syncthreads();
    for (int i = ty; i < 32; i += 8) {
        int cc = c0 + i, r = r0 + tx;
        if (cc < C && r < R) out[(size_t)cc * R + r] = f2bf(tile[tx][i]);
    }
}

__global__ __launch_bounds__(256) void k_tail(const int* __restrict__ captions,
                                              const int* __restrict__ caption_len,
                                              float* __restrict__ out) {
    int i = blockIdx.x * 256 + threadIdx.x;
    if (i < Bn * Tn) {
        out[OUT_CAPT + i] = (float)captions[i];
    } else if (i < Bn * Tn + Bn) {
        int b = i - Bn * Tn;
        out[OUT_SEQ + b] = (float)(caption_len[b] - 1);
    }
}

// ================= per-step kernel A: hdec + raw scores (verbatim R14) =================
__global__ __launch_bounds__(256) void k_scores(const unsigned short* __restrict__ enc_proj,
                                                const float* __restrict__ hbase, int hstride,
                                                const float* __restrict__ W_dec,
                                                const float* __restrict__ b_dec,
                                                const float* __restrict__ W_att,
                                                const float* __restrict__ b_att,
                                                float* __restrict__ scores) {
    __shared__ float hv[DECn];
    __shared__ float hs[ATTn];
    __shared__ float wa[ATTn];
    int bid = blockIdx.x;
    int b = bid >> 2, q = bid & 3;
    int tid = threadIdx.x;
    hv[tid]       = hbase[(size_t)b * hstride + tid];
    hv[tid + 256] = hbase[(size_t)b * hstride + tid + 256];
    wa[tid]       = W_att[tid];
    wa[tid + 256] = W_att[tid + 256];
    __syncthreads();
    {
        float acc0 = b_dec[tid], acc1 = b_dec[tid + 256];
        const float* wd = W_dec + tid;
        #pragma unroll 8
        for (int k = 0; k < DECn; ++k) {
            float h = hv[k];
            acc0 += h * wd[(size_t)k * DECn];
            acc1 += h * wd[(size_t)k * DECn + 256];
        }
        hs[tid] = acc0;
        hs[tid + 256] = acc1;
    }
    __syncthreads();
    int wv = tid >> 6, lane = tid & 63;
    float batt = b_att[0];
    for (int p = q * 49 + wv; p < q * 49 + 49; p += 4) {
        const unsigned short* ep = enc_proj + ((size_t)b * Pn + p) * ATTn;
        float s = 0.f;
        #pragma unroll
        for (int a = lane; a < ATTn; a += 64) {
            float v = bf2f(ep[a]) + hs[a];
            s += fmaxf(v, 0.f) * wa[a];
        }
        #pragma unroll
        for (int off = 32; off > 0; off >>= 1) s += __shfl_xor(s, off);
        if (lane == 0) scores[(size_t)b * Pn + p] = s + batt;
    }
}

// ================= per-step kernel B: softmax + gates + LSTM (reg-prefetch Fih) =================
// 512 blocks: b = bid>>3, ds = bid&7. thread: gate = tid>>6, dd = tid&63;
// g = gate*512 + ds*64 + dd.
__global__ __launch_bounds__(256) void k_gates2(const unsigned short* __restrict__ WT,
                                                const unsigned short* __restrict__ Fih,
                                                const float* __restrict__ emb,
                                                const int* __restrict__ captions,
                                                const float* __restrict__ scores,
                                                const float* __restrict__ hbase, int hstride,
                                                const float* __restrict__ b_ih,
                                                const float* __restrict__ b_hh,
                                                float* __restrict__ c,
                                                float* __restrict__ hall,
                                                float* __restrict__ alphas_out, int t) {
    __shared__ float al[Pn];
    __shared__ float red[4];
    __shared__ float Aemb[En];
    __shared__ float Ah2[DECn];
    __shared__ unsigned short Ftile[48][256];
    __shared__ float sg[4][64];
    int bid = blockIdx.x;
    int b = bid >> 3, ds = bid & 7;
    int tid = threadIdx.x;
    int gate = tid >> 6, dd = tid & 63;
    int g = (gate << 9) + ds * 64 + dd;

    // softmax (redundant per ds; R14 reduction order)
    int wv = tid >> 6, lane = tid & 63;
    float v = (tid < Pn) ? scores[(size_t)b * Pn + tid] : -1e30f;
    float m = v;
    #pragma unroll
    for (int off = 32; off > 0; off >>= 1) m = fmaxf(m, __shfl_xor(m, off));
    if (lane == 0) red[wv] = m;
    __syncthreads();
    float M = fmaxf(fmaxf(red[0], red[1]), fmaxf(red[2], red[3]));
    __syncthreads();
    float e = (tid < Pn) ? expf(v - M) : 0.f;
    float s = e;
    #pragma unroll
    for (int off = 32; off > 0; off >>= 1) s += __shfl_xor(s, off);
    if (lane == 0) red[wv] = s;
    __syncthreads();
    float S = red[0] + red[1] + red[2] + red[3];
    float an = e / S;
    if (tid < Pn) {
        al[tid] = an;
        if (ds == 0) alphas_out[((size_t)b * STEPSn + t) * Pn + tid] = an;
    }
    // stage emb + h
    const float* er = emb + (size_t)captions[b * Tn + t] * En;
    for (int k = tid; k < En; k += 256) Aemb[k] = er[k];
    for (int k = tid; k < DECn; k += 256) Ah2[k] = hbase[(size_t)b * hstride + k];
    __syncthreads();

    const unsigned short* fb = Fih + (size_t)b * Pn * Gn;
    auto ldF = [&](int p0_, int q) -> short8 {
        int pr = q >> 5, j = q & 31;
        int seg = j >> 3, s8 = (j & 7) * 8;
        return *(const short8*)&fb[(size_t)(p0_ + pr) * Gn + ((seg << 9) + ds * 64 + s8)];
    };
    auto stF = [&](int q, short8 vv8) {
        int pr = q >> 5, j = q & 31;
        int seg = j >> 3, s8 = (j & 7) * 8;
        *(short8*)&Ftile[pr][seg * 64 + s8] = vv8;
    };

    float acc = b_ih[g] + b_hh[g];

    // issue chunk-0 Fih loads early (hidden under emb MAC)
    short8 r0 = ldF(0, tid);
    short8 r1 = ldF(0, tid + 256);
    short8 r2 = ldF(0, tid + 512);
    short8 r3 = ldF(0, tid + 768);
    short8 r4 = ldF(0, tid + 1024);
    short8 r5 = ldF(0, tid + 1280);

    // emb part
    #pragma unroll 4
    for (int k = 0; k < En; ++k)
        acc += Aemb[k] * bf2f(WT[(size_t)k * Gn + g]);

    // Fih part: 4 chunks of 48 + tail 4; single-buffer, reg-prefetch
    int p0 = 0;
    #pragma unroll
    for (int pc = 0; pc < 4; ++pc) {
        __syncthreads();
        stF(tid, r0); stF(tid + 256, r1); stF(tid + 512, r2);
        stF(tid + 768, r3); stF(tid + 1024, r4); stF(tid + 1280, r5);
        __syncthreads();
        if (pc < 3) {
            int np = p0 + 48;
            r0 = ldF(np, tid); r1 = ldF(np, tid + 256); r2 = ldF(np, tid + 512);
            r3 = ldF(np, tid + 768); r4 = ldF(np, tid + 1024); r5 = ldF(np, tid + 1280);
        } else if (tid < 128) {
            r0 = ldF(p0 + 48, tid);   // tail (4 rows = 128 tasks)
        }
        #pragma unroll 4
        for (int pr = 0; pr < 48; ++pr)
            acc += al[p0 + pr] * bf2f(Ftile[pr][tid]);
        p0 += 48;
    }
    __syncthreads();
    if (tid < 128) stF(tid, r0);
    __syncthreads();
    #pragma unroll
    for (int pr = 0; pr < 4; ++pr)
        acc += al[p0 + pr] * bf2f(Ftile[pr][tid]);

    // h part (real W_hh^T)
    #pragma unroll 4
    for (int k = 0; k < DECn; ++k)
        acc += Ah2[k] * bf2f(WT[(size_t)(KIH + k) * Gn + g]);

    sg[gate][dd] = acc;
    __syncthreads();
    if (tid < 64) {
        float gi = sg[0][tid], gf = sg[1][tid];
        float gg = sg[2][tid], go = sg[3][tid];
        int d = ds * 64 + tid;
        float si = 1.f / (1.f + expf(-gi));
        float sf = 1.f / (1.f + expf(-gf));
        float so = 1.f / (1.f + expf(-go));
        size_t cidx = (size_t)b * DECn + d;
        float cc = sf * c[cidx] + si * tanhf(gg);
        float hh = so * tanhf(cc);
        c[cidx] = cc;
        hall[((size_t)b * STEPSn + t) * DECn + d] = hh;
    }
}

// ================= logits: 1-pass bf16 MFMA =================

__global__ __launch_bounds__(256) void k_hall2bf(const float* __restrict__ hall,
                                                 short* __restrict__ Ah) {
    int idx = blockIdx.x * 256 + threadIdx.x;
    size_t base = (size_t)idx * 4;
    float4 v = *(const float4*)(hall + base);
    short4v h;
    h[0] = (short)f2bf(v.x); h[1] = (short)f2bf(v.y);
    h[2] = (short)f2bf(v.z); h[3] = (short)f2bf(v.w);
    *(short4v*)(Ah + base) = h;
}

__global__ __launch_bounds__(512) void k_logits_mfma(const short* __restrict__ Ah,
                                                     const float* __restrict__ W_out,
                                                     const float* __restrict__ b_out,
                                                     float* __restrict__ out) {
    __shared__ short Bh[48][520];   // 49,920 B -> 2-3 blocks/CU
    int n0 = blockIdx.x * 48;
    int tid = threadIdx.x;
    for (int q = tid; q < 6144; q += 512) {
        int cq = q % 12, k = q / 12;
        const float* src = W_out + (size_t)k * Vn + n0 + cq * 4;
        float4 v = *(const float4*)src;
        Bh[cq * 4 + 0][k] = (short)f2bf(v.x);
        Bh[cq * 4 + 1][k] = (short)f2bf(v.y);
        Bh[cq * 4 + 2][k] = (short)f2bf(v.z);
        Bh[cq * 4 + 3][k] = (short)f2bf(v.w);
    }
    __syncthreads();
    int w = tid >> 6, l = tid & 63;
    int lr = l & 15, lk = (l >> 4) * 8;
    float bias[3];
    #pragma unroll
    for (int nt = 0; nt < 3; ++nt) bias[nt] = b_out[n0 + nt * 16 + lr];

    for (int chunk = 0; chunk < 10; ++chunk) {
        int m0 = chunk * 128 + w * 16;
        f32x4 acc[3];
        #pragma unroll
        for (int nt = 0; nt < 3; ++nt) acc[nt] = (f32x4){0.f, 0.f, 0.f, 0.f};
        #pragma unroll 4
        for (int ks = 0; ks < 16; ++ks) {
            int k0 = ks * 32;
            short8 ah = *(const short8*)(Ah + (size_t)(m0 + lr) * DECn + k0 + lk);
            #pragma unroll
            for (int nt = 0; nt < 3; ++nt) {
                short8 bh = *(const short8*)&Bh[nt * 16 + lr][k0 + lk];
                acc[nt] = __builtin_amdgcn_mfma_f32_16x16x32_bf16(ah, bh, acc[nt], 0, 0, 0);
            }
        }
        #pragma unroll
        for (int nt = 0; nt < 3; ++nt) {
            int n = n0 + nt * 16 + lr;
            #pragma unroll
            for (int r = 0; r < 4; ++r) {
                int m = m0 + (l >> 4) * 4 + r;
                out[(size_t)m * Vn + n] = acc[nt][r] + bias[nt];
            }
        }
    }
}

// ================= launcher =================

extern "C" void kernel_launch(void* const* d_in, const int* in_sizes, int n_in,
                              void* d_out, int out_size, void* d_ws, size_t ws_size,
                              hipStream_t stream) {
    const float* features    = (const float*)d_in[0];
    const int*   captions    = (const int*)d_in[1];
    const int*   caption_len = (const int*)d_in[2];
    const float* emb         = (const float*)d_in[3];
    const float* W_enc       = (const float*)d_in[4];
    const float* b_enc       = (const float*)d_in[5];
    const float* W_dec       = (const float*)d_in[6];
    const float* b_dec       = (const float*)d_in[7];
    const float* W_att       = (const float*)d_in[8];
    const float* b_att       = (const float*)d_in[9];
    const float* W_h0        = (const float*)d_in[10];
    const float* b_h0        = (const float*)d_in[11];
    const float* W_c0        = (const float*)d_in[12];
    const float* b_c0        = (const float*)d_in[13];
    const float* W_ih        = (const float*)d_in[14];
    const float* b_ih        = (const float*)d_in[15];
    const float* W_hh        = (const float*)d_in[16];
    const float* b_hh        = (const float*)d_in[17];
    const float* W_out       = (const float*)d_in[18];
    const float* b_out       = (const float*)d_in[19];

    float* out = (float*)d_out;
    float* ws  = (float*)d_ws;

    unsigned short* ws_encproj = (unsigned short*)(ws + WS_ENCPROJ);
    unsigned short* ws_wct     = ws_encproj + (size_t)Bn * Pn * ATTn;  // tail of encproj region
    unsigned short* ws_WT      = (unsigned short*)(ws + WS_WT);        // [2860][2048] bf16
    float* ws_meanf   = ws + WS_CTX;
    float* ws_h0      = ws + WS_H0;
    float* ws_c       = ws + WS_C;
    float* ws_hall    = ws + WS_HALL;
    float* ws_scores  = ws + WS_SCORES;
    short* ws_Ah      = (short*)(ws + WS_ENCPROJ);       // reuse enc_proj region post-loop
    unsigned short* fih = (unsigned short*)out;          // Fih stash in logits region

    // ---- precompute ----
    k_wct<<<dim3(Gn), 256, 0, stream>>>(W_ih, ws_wct);
    k_transpose_bf<<<dim3((KIH + 31) / 32, Gn / 32), 256, 0, stream>>>(
        W_ih, ws_WT, Gn, KIH);
    k_transpose_bf<<<dim3((DECn + 31) / 32, Gn / 32), 256, 0, stream>>>(
        W_hh, ws_WT + (size_t)KIH * Gn, Gn, DECn);       // real W_hh^T
    k_encproj_mfma<<<dim3(Pn * Bn / 128, ATTn / 128), 256, 0, stream>>>(
        features, W_enc, b_enc, ws_encproj);
    k_fih<<<dim3(Gn / 128, Pn * Bn / 128), 256, 0, stream>>>(features, ws_wct, fih);
    k_mean<<<dim3(Bn, ENCn / 256), 256, 0, stream>>>(features, ws_meanf);
    k_init_state<<<dim3(2, 16), 256, 0, stream>>>(ws_meanf, W_h0, b_h0, W_c0, b_c0,
                                                  ws_h0, ws_c);
    k_tail<<<dim3((Bn * Tn + Bn + 255) / 256), 256, 0, stream>>>(captions, caption_len, out);

    // ---- recurrence: 2 kernels per step ----
    for (int t = 0; t < STEPSn; ++t) {
        const float* hbase = (t == 0) ? ws_h0 : (ws_hall + (size_t)(t - 1) * DECn);
        int hstride = (t == 0) ? DECn : (STEPSn * DECn);
        k_scores<<<dim3(256), 256, 0, stream>>>(ws_encproj, hbase, hstride,
                                                W_dec, b_dec, W_att, b_att, ws_scores);
        k_gates2<<<dim3(512), 256, 0, stream>>>(ws_WT, fih, emb, captions, ws_scores,
                                                hbase, hstride, b_ih, b_hh,
                                                ws_c, ws_hall, out + OUT_ALPHAS, t);
    }

    // ---- logits: bf16 A, then 1-pass MFMA GEMM (overwrites Fih stash) ----
    k_hall2bf<<<dim3(Bn * STEPSn * DECn / 1024), 256, 0, stream>>>(ws_hall, ws_Ah);
    k_logits_mfma<<<dim3(Vn / 48), 512, 0, stream>>>(ws_Ah, W_out, b_out, out);
}

// Round 16
// 2885.389 us; speedup vs baseline: 1.1461x; 1.0687x over previous
//
#include <hip/hip_runtime.h>
#include <hip/hip_bf16.h>
#include <hip/hip_fp8.h>
#include <cstdint>
#include <cstddef>

// Problem constants
#define Bn 64
#define Pn 196
#define ENCn 2048
#define DECn 512
#define ATTn 512
#define En 300
#define Vn 30000
#define Tn 21
#define STEPSn 20
#define Gn 2048        // 4*DEC gate width
#define KIH 2348       // En + ENCn  (W_ih^T rows)

// ---- workspace layout (float offsets) ----
#define WS_ENCPROJ ((size_t)0)                            // bf16 enc_proj [12544][512] ushort; tail holds WCT; reused post-loop for Ah
#define WS_WT    (WS_ENCPROJ + (size_t)Bn*Pn*ATTn)        // bf16 [2860][2048] ushort
#define WS_CTX   (WS_WT + (size_t)KIH*Gn)                 // [64][2048] mean_f (pre only)
#define WS_H0    (WS_CTX + (size_t)Bn*ENCn)               // [64][512]
#define WS_C     (WS_H0 + (size_t)Bn*DECn)                // [64][512]
#define WS_HALL  (WS_C + (size_t)Bn*DECn)                 // [64][20][512]
#define WS_SCORES (WS_HALL + (size_t)Bn*STEPSn*DECn)      // [64][196]

// ---- output layout (float offsets into d_out) ----
#define OUT_ALPHAS ((size_t)Bn*STEPSn*Vn)
#define OUT_CAPT   (OUT_ALPHAS + (size_t)Bn*STEPSn*Pn)
#define OUT_SEQ    (OUT_CAPT + (size_t)Bn*Tn)
// During the loop, d_out's logits region holds Fih fp8 [12544][2048] (25.7 MB).

typedef __attribute__((ext_vector_type(8))) short short8;
typedef __attribute__((ext_vector_type(4))) short short4v;
typedef __attribute__((ext_vector_type(4))) float f32x4;
typedef __attribute__((ext_vector_type(8))) unsigned char uchar8;

static __device__ __forceinline__ unsigned short f2bf(float f) {
    unsigned u = __float_as_uint(f);
    return (unsigned short)((u + 0x7FFFu + ((u >> 16) & 1u)) >> 16);
}
static __device__ __forceinline__ float bf2f(unsigned short u) {
    return __uint_as_float((unsigned)u << 16);
}
static __device__ __forceinline__ unsigned char f2e4(float f) {
    __hip_fp8_e4m3 v(f);
    return (unsigned char)v.__x;
}
static __device__ __forceinline__ float e42f(unsigned char u) {
    __hip_fp8_e4m3 v;
    v.__x = (__hip_fp8_storage_t)u;
    return (float)v;
}

// ============ enc_proj via split-bf16 MFMA; bf16 output (verbatim R15) ============
__global__ __launch_bounds__(256) void k_encproj_mfma(
        const float* __restrict__ A,
        const float* __restrict__ B,
        const float* __restrict__ bias,
        unsigned short* __restrict__ Cbf) {
    __shared__ short Ah[128][40];
    __shared__ short Al[128][40];
    __shared__ short Bh[128][40];
    __shared__ short Bl[128][40];
    int m0 = blockIdx.x * 128, n0 = blockIdx.y * 128;
    int tid = threadIdx.x;
    int w = tid >> 6, l = tid & 63;
    int lr = l & 15, lk = (l >> 4) * 8;

    f32x4 acc[2][8];
    #pragma unroll
    for (int mt = 0; mt < 2; ++mt)
        #pragma unroll
        for (int nt = 0; nt < 8; ++nt) acc[mt][nt] = (f32x4){0.f, 0.f, 0.f, 0.f};

    for (int k0 = 0; k0 < ENCn; k0 += 32) {
        __syncthreads();
        #pragma unroll
        for (int i = 0; i < 2; ++i) {
            int q = tid + i * 256;
            int r = q >> 2, c8 = (q & 3) * 8;
            const float* src = A + (size_t)(m0 + r) * ENCn + k0 + c8;
            float4 v0 = *(const float4*)src;
            float4 v1 = *(const float4*)(src + 4);
            float vv[8] = {v0.x, v0.y, v0.z, v0.w, v1.x, v1.y, v1.z, v1.w};
            short8 h8, l8;
            #pragma unroll
            for (int j = 0; j < 8; ++j) {
                unsigned short hi = f2bf(vv[j]);
                float rem = vv[j] - __uint_as_float((unsigned)hi << 16);
                h8[j] = (short)hi;
                l8[j] = (short)f2bf(rem);
            }
            *(short8*)&Ah[r][c8] = h8;
            *(short8*)&Al[r][c8] = l8;
        }
        #pragma unroll
        for (int i = 0; i < 2; ++i) {
            int q = tid + i * 256;
            int n = q & 127, kc = (q >> 7) * 8;
            float vv[8];
            #pragma unroll
            for (int j = 0; j < 8; ++j)
                vv[j] = B[(size_t)(k0 + kc + j) * ATTn + n0 + n];
            short8 h8, l8;
            #pragma unroll
            for (int j = 0; j < 8; ++j) {
                unsigned short hi = f2bf(vv[j]);
                float rem = vv[j] - __uint_as_float((unsigned)hi << 16);
                h8[j] = (short)hi;
                l8[j] = (short)f2bf(rem);
            }
            *(short8*)&Bh[n][kc] = h8;
            *(short8*)&Bl[n][kc] = l8;
        }
        __syncthreads();
        short8 ah[2], al2[2];
        #pragma unroll
        for (int mt = 0; mt < 2; ++mt) {
            int row = w * 32 + mt * 16 + lr;
            ah[mt]  = *(const short8*)&Ah[row][lk];
            al2[mt] = *(const short8*)&Al[row][lk];
        }
        #pragma unroll
        for (int nt = 0; nt < 8; ++nt) {
            short8 bh = *(const short8*)&Bh[nt * 16 + lr][lk];
            short8 bl = *(const short8*)&Bl[nt * 16 + lr][lk];
            #pragma unroll
            for (int mt = 0; mt < 2; ++mt) {
                acc[mt][nt] = __builtin_amdgcn_mfma_f32_16x16x32_bf16(ah[mt], bh, acc[mt][nt], 0, 0, 0);
                acc[mt][nt] = __builtin_amdgcn_mfma_f32_16x16x32_bf16(ah[mt], bl, acc[mt][nt], 0, 0, 0);
                acc[mt][nt] = __builtin_amdgcn_mfma_f32_16x16x32_bf16(al2[mt], bh, acc[mt][nt], 0, 0, 0);
            }
        }
    }
    #pragma unroll
    for (int mt = 0; mt < 2; ++mt) {
        #pragma unroll
        for (int nt = 0; nt < 8; ++nt) {
            int n = n0 + nt * 16 + lr;
            float bv = bias[n];
            #pragma unroll
            for (int r = 0; r < 4; ++r) {
                int m = m0 + w * 32 + mt * 16 + (l >> 4) * 4 + r;
                Cbf[(size_t)m * ATTn + n] = f2bf(acc[mt][nt][r] + bv);
            }
        }
    }
}

// ============ Fih = features @ WCT^T : 1-pass bf16 MFMA, fp8 output ============
// grid (16, 98): x = n-tile (consecutive blocks share A-panel -> L2/L3 hot).
__global__ __launch_bounds__(256) void k_fih(const float* __restrict__ A,
                                             const unsigned short* __restrict__ WCT,
                                             unsigned char* __restrict__ Cf8) {
    __shared__ short Ahs[128][40];
    __shared__ short Bs[128][40];
    int n0 = blockIdx.x * 128, m0 = blockIdx.y * 128;
    int tid = threadIdx.x;
    int w = tid >> 6, l = tid & 63;
    int lr = l & 15, lk = (l >> 4) * 8;

    f32x4 acc[2][8];
    #pragma unroll
    for (int mt = 0; mt < 2; ++mt)
        #pragma unroll
        for (int nt = 0; nt < 8; ++nt) acc[mt][nt] = (f32x4){0.f, 0.f, 0.f, 0.f};

    for (int k0 = 0; k0 < ENCn; k0 += 32) {
        __syncthreads();
        #pragma unroll
        for (int i = 0; i < 2; ++i) {
            int q = tid + i * 256;
            int r = q >> 2, c8 = (q & 3) * 8;
            const float* src = A + (size_t)(m0 + r) * ENCn + k0 + c8;
            float4 v0 = *(const float4*)src;
            float4 v1 = *(const float4*)(src + 4);
            float vv[8] = {v0.x, v0.y, v0.z, v0.w, v1.x, v1.y, v1.z, v1.w};
            short8 h8;
            #pragma unroll
            for (int j = 0; j < 8; ++j) h8[j] = (short)f2bf(vv[j]);
            *(short8*)&Ahs[r][c8] = h8;
        }
        #pragma unroll
        for (int i = 0; i < 2; ++i) {
            int q = tid + i * 256;
            int n = q >> 2, kc = (q & 3) * 8;
            *(short8*)&Bs[n][kc] =
                *(const short8*)&WCT[(size_t)(n0 + n) * ENCn + k0 + kc];
        }
        __syncthreads();
        short8 ah[2];
        #pragma unroll
        for (int mt = 0; mt < 2; ++mt) {
            int row = w * 32 + mt * 16 + lr;
            ah[mt] = *(const short8*)&Ahs[row][lk];
        }
        #pragma unroll
        for (int nt = 0; nt < 8; ++nt) {
            short8 bs = *(const short8*)&Bs[nt * 16 + lr][lk];
            #pragma unroll
            for (int mt = 0; mt < 2; ++mt) {
                acc[mt][nt] = __builtin_amdgcn_mfma_f32_16x16x32_bf16(ah[mt], bs, acc[mt][nt], 0, 0, 0);
            }
        }
    }
    #pragma unroll
    for (int mt = 0; mt < 2; ++mt) {
        #pragma unroll
        for (int nt = 0; nt < 8; ++nt) {
            int n = n0 + nt * 16 + lr;
            #pragma unroll
            for (int r = 0; r < 4; ++r) {
                int m = m0 + w * 32 + mt * 16 + (l >> 4) * 4 + r;
                Cf8[(size_t)m * Gn + n] = f2e4(acc[mt][nt][r]);
            }
        }
    }
}

// ================= small precompute kernels =================

// WCT[g][k] = bf16(W_ih[g][En+k])
__global__ __launch_bounds__(256) void k_wct(const float* __restrict__ W_ih,
                                             unsigned short* __restrict__ WCT) {
    int g = blockIdx.x;
    int k8 = threadIdx.x * 8;
    const float* src = W_ih + (size_t)g * KIH + En + k8;
    float4 v0 = *(const float4*)src;
    float4 v1 = *(const float4*)(src + 4);
    float vv[8] = {v0.x, v0.y, v0.z, v0.w, v1.x, v1.y, v1.z, v1.w};
    short8 o;
    #pragma unroll
    for (int j = 0; j < 8; ++j) o[j] = (short)f2bf(vv[j]);
    *(short8*)&WCT[(size_t)g * ENCn + k8] = o;
}

__global__ __launch_bounds__(256) void k_mean(const float* __restrict__ feat,
                                              float* __restrict__ mean_f) {
    int b = blockIdx.x;
    int e = blockIdx.y * 256 + threadIdx.x;
    const float* fb = feat + (size_t)b * Pn * ENCn + e;
    float s = 0.f;
    #pragma unroll 4
    for (int p = 0; p < Pn; ++p) s += fb[(size_t)p * ENCn];
    mean_f[(size_t)b * ENCn + e] = s * (1.0f / (float)Pn);
}

// split-K init: grid (8, 64): x = 64-col tile, y = batch. 4-way K partials.
__global__ __launch_bounds__(256) void k_init_state(
        const float* __restrict__ mf,
        const float* __restrict__ Wh, const float* __restrict__ bh,
        const float* __restrict__ Wc, const float* __restrict__ bc,
        float* __restrict__ h, float* __restrict__ c) {
    __shared__ float mfs[ENCn];
    __shared__ float part[2][4][64];
    int n0 = blockIdx.x * 64;
    int b = blockIdx.y;
    int tid = threadIdx.x;
    int nn = tid & 63, kq = tid >> 6;
    for (int k = tid; k < ENCn; k += 256) mfs[k] = mf[(size_t)b * ENCn + k];
    __syncthreads();
    float ah = 0.f, ac = 0.f;
    int kb = kq * 512;
    #pragma unroll 4
    for (int k = 0; k < 512; ++k) {
        float a = mfs[kb + k];
        ah += a * Wh[(size_t)(kb + k) * DECn + n0 + nn];
        ac += a * Wc[(size_t)(kb + k) * DECn + n0 + nn];
    }
    part[0][kq][nn] = ah;
    part[1][kq][nn] = ac;
    __syncthreads();
    if (tid < 64) {
        float s = bh[n0 + tid] + part[0][0][tid] + part[0][1][tid]
                + part[0][2][tid] + part[0][3][tid];
        h[(size_t)b * DECn + n0 + tid] = s;
    } else if (tid < 128) {
        int n2 = tid - 64;
        float s = bc[n0 + n2] + part[1][0][n2] + part[1][1][n2]
                + part[1][2][n2] + part[1][3][n2];
        c[(size_t)b * DECn + n0 + n2] = s;
    }
}

// transpose in[R][C] fp32 -> out[C][R] bf16
__global__ __launch_bounds__(256) void k_transpose_bf(const float* __restrict__ in,
                                                      unsigned short* __restrict__ out,
                                                      int R, int C) {
    __shared__ float tile[32][33];
    int c0 = blockIdx.x * 32, r0 = blockIdx.y * 32;
    int tx = threadIdx.x & 31, ty = threadIdx.x >> 5;
    for (int i = ty; i < 32; i += 8) {
        int r = r0 + i, cc = c0 + tx;
        tile[i][tx] = (r < R && cc < C) ? in[(size_t)r * C + cc] : 0.f;
    }
    __syncthreads();
    for (int i = ty; i < 32; i += 8) {
        int cc = c0 + i, r = r0 + tx;
        if (cc < C && r < R) out[(size_t)cc * R + r] = f2bf(tile[tx][i]);
    }
}

__global__ __launch_bounds__(256) void k_tail(const int* __restrict__ captions,
                                              const int* __restrict__ caption_len,
                                              float* __restrict__ out) {
    int i = blockIdx.x * 256 + threadIdx.x;
    if (i < Bn * Tn) {
        out[OUT_CAPT + i] = (float)captions[i];
    } else if (i < Bn * Tn + Bn) {
        int b = i - Bn * Tn;
        out[OUT_SEQ + b] = (float)(caption_len[b] - 1);
    }
}

// ================= per-step kernel A: hdec + raw scores (verbatim R15) =================
__global__ __launch_bounds__(256) void k_scores(const unsigned short* __restrict__ enc_proj,
                                                const float* __restrict__ hbase, int hstride,
                                                const float* __restrict__ W_dec,
                                                const float* __restrict__ b_dec,
                                                const float* __restrict__ W_att,
                                                const float* __restrict__ b_att,
                                                float* __restrict__ scores) {
    __shared__ float hv[DECn];
    __shared__ float hs[ATTn];
    __shared__ float wa[ATTn];
    int bid = blockIdx.x;
    int b = bid >> 2, q = bid & 3;
    int tid = threadIdx.x;
    hv[tid]       = hbase[(size_t)b * hstride + tid];
    hv[tid + 256] = hbase[(size_t)b * hstride + tid + 256];
    wa[tid]       = W_att[tid];
    wa[tid + 256] = W_att[tid + 256];
    __syncthreads();
    {
        float acc0 = b_dec[tid], acc1 = b_dec[tid + 256];
        const float* wd = W_dec + tid;
        #pragma unroll 8
        for (int k = 0; k < DECn; ++k) {
            float h = hv[k];
            acc0 += h * wd[(size_t)k * DECn];
            acc1 += h * wd[(size_t)k * DECn + 256];
        }
        hs[tid] = acc0;
        hs[tid + 256] = acc1;
    }
    __syncthreads();
    int wv = tid >> 6, lane = tid & 63;
    float batt = b_att[0];
    for (int p = q * 49 + wv; p < q * 49 + 49; p += 4) {
        const unsigned short* ep = enc_proj + ((size_t)b * Pn + p) * ATTn;
        float s = 0.f;
        #pragma unroll
        for (int a = lane; a < ATTn; a += 64) {
            float v = bf2f(ep[a]) + hs[a];
            s += fmaxf(v, 0.f) * wa[a];
        }
        #pragma unroll
        for (int off = 32; off > 0; off >>= 1) s += __shfl_xor(s, off);
        if (lane == 0) scores[(size_t)b * Pn + p] = s + batt;
    }
}

// ================= per-step kernel B: softmax + gates + LSTM (fp8 Fih) =================
// 512 blocks: b = bid>>3, ds = bid&7. g = (tid>>6)*512 + ds*64 + (tid&63).
__global__ __launch_bounds__(256) void k_gates2(const unsigned short* __restrict__ WT,
                                                const unsigned char* __restrict__ Fih,
                                                const float* __restrict__ emb,
                                                const int* __restrict__ captions,
                                                const float* __restrict__ scores,
                                                const float* __restrict__ hbase, int hstride,
                                                const float* __restrict__ b_ih,
                                                const float* __restrict__ b_hh,
                                                float* __restrict__ c,
                                                float* __restrict__ hall,
                                                float* __restrict__ alphas_out, int t) {
    __shared__ float al[Pn];
    __shared__ float red[4];
    __shared__ float Aemb[En];
    __shared__ float Ah2[DECn];
    __shared__ unsigned char Ftile[48][256];
    __shared__ float sg[4][64];
    int bid = blockIdx.x;
    int b = bid >> 3, ds = bid & 7;
    int tid = threadIdx.x;
    int gate = tid >> 6, dd = tid & 63;
    int g = (gate << 9) + ds * 64 + dd;

    // softmax (redundant per ds)
    int wv = tid >> 6, lane = tid & 63;
    float v = (tid < Pn) ? scores[(size_t)b * Pn + tid] : -1e30f;
    float m = v;
    #pragma unroll
    for (int off = 32; off > 0; off >>= 1) m = fmaxf(m, __shfl_xor(m, off));
    if (lane == 0) red[wv] = m;
    __syncthreads();
    float M = fmaxf(fmaxf(red[0], red[1]), fmaxf(red[2], red[3]));
    __syncthreads();
    float e = (tid < Pn) ? expf(v - M) : 0.f;
    float s = e;
    #pragma unroll
    for (int off = 32; off > 0; off >>= 1) s += __shfl_xor(s, off);
    if (lane == 0) red[wv] = s;
    __syncthreads();
    float S = red[0] + red[1] + red[2] + red[3];
    float an = e / S;
    if (tid < Pn) {
        al[tid] = an;
        if (ds == 0) alphas_out[((size_t)b * STEPSn + t) * Pn + tid] = an;
    }
    // stage emb + h
    const float* er = emb + (size_t)captions[b * Tn + t] * En;
    for (int k = tid; k < En; k += 256) Aemb[k] = er[k];
    for (int k = tid; k < DECn; k += 256) Ah2[k] = hbase[(size_t)b * hstride + k];
    __syncthreads();

    const unsigned char* fb = Fih + (size_t)b * Pn * Gn;
    auto ldF = [&](int p0_, int q) -> uchar8 {
        int pr = q >> 5, j = q & 31;
        int seg = j >> 3, s8 = (j & 7) * 8;
        return *(const uchar8*)&fb[(size_t)(p0_ + pr) * Gn + ((seg << 9) + ds * 64 + s8)];
    };
    auto stF = [&](int q, uchar8 vv8) {
        int pr = q >> 5, j = q & 31;
        int seg = j >> 3, s8 = (j & 7) * 8;
        *(uchar8*)&Ftile[pr][seg * 64 + s8] = vv8;
    };

    float acc = b_ih[g] + b_hh[g];

    // issue chunk-0 Fih loads early (hidden under emb MAC)
    uchar8 r0 = ldF(0, tid);
    uchar8 r1 = ldF(0, tid + 256);
    uchar8 r2 = ldF(0, tid + 512);
    uchar8 r3 = ldF(0, tid + 768);
    uchar8 r4 = ldF(0, tid + 1024);
    uchar8 r5 = ldF(0, tid + 1280);

    // emb part
    #pragma unroll 4
    for (int k = 0; k < En; ++k)
        acc += Aemb[k] * bf2f(WT[(size_t)k * Gn + g]);

    // Fih part: 4 chunks of 48 + tail 4; reg-prefetch
    int p0 = 0;
    #pragma unroll
    for (int pc = 0; pc < 4; ++pc) {
        __syncthreads();
        stF(tid, r0); stF(tid + 256, r1); stF(tid + 512, r2);
        stF(tid + 768, r3); stF(tid + 1024, r4); stF(tid + 1280, r5);
        __syncthreads();
        if (pc < 3) {
            int np = p0 + 48;
            r0 = ldF(np, tid); r1 = ldF(np, tid + 256); r2 = ldF(np, tid + 512);
            r3 = ldF(np, tid + 768); r4 = ldF(np, tid + 1024); r5 = ldF(np, tid + 1280);
        } else if (tid < 128) {
            r0 = ldF(p0 + 48, tid);   // tail (4 rows = 128 tasks)
        }
        #pragma unroll 4
        for (int pr = 0; pr < 48; ++pr)
            acc += al[p0 + pr] * e42f(Ftile[pr][tid]);
        p0 += 48;
    }
    __syncthreads();
    if (tid < 128) stF(tid, r0);
    __syncthreads();
    #pragma unroll
    for (int pr = 0; pr < 4; ++pr)
        acc += al[p0 + pr] * e42f(Ftile[pr][tid]);

    // h part (W_hh^T)
    #pragma unroll 4
    for (int k = 0; k < DECn; ++k)
        acc += Ah2[k] * bf2f(WT[(size_t)(KIH + k) * Gn + g]);

    sg[gate][dd] = acc;
    __syncthreads();
    if (tid < 64) {
        float gi = sg[0][tid], gf = sg[1][tid];
        float gg = sg[2][tid], go = sg[3][tid];
        int d = ds * 64 + tid;
        float si = 1.f / (1.f + expf(-gi));
        float sf = 1.f / (1.f + expf(-gf));
        float so = 1.f / (1.f + expf(-go));
        size_t cidx = (size_t)b * DECn + d;
        float cc = sf * c[cidx] + si * tanhf(gg);
        float hh = so * tanhf(cc);
        c[cidx] = cc;
        hall[((size_t)b * STEPSn + t) * DECn + d] = hh;
    }
}

// ================= logits: 1-pass bf16 MFMA (verbatim R15) =================

__global__ __launch_bounds__(256) void k_hall2bf(const float* __restrict__ hall,
                                                 short* __restrict__ Ah) {
    int idx = blockIdx.x * 256 + threadIdx.x;
    size_t base = (size_t)idx * 4;
    float4 v = *(const float4*)(hall + base);
    short4v h;
    h[0] = (short)f2bf(v.x); h[1] = (short)f2bf(v.y);
    h[2] = (short)f2bf(v.z); h[3] = (short)f2bf(v.w);
    *(short4v*)(Ah + base) = h;
}

__global__ __launch_bounds__(512) void k_logits_mfma(const short* __restrict__ Ah,
                                                     const float* __restrict__ W_out,
                                                     const float* __restrict__ b_out,
                                                     float* __restrict__ out) {
    __shared__ short Bh[48][520];
    int n0 = blockIdx.x * 48;
    int tid = threadIdx.x;
    for (int q = tid; q < 6144; q += 512) {
        int cq = q % 12, k = q / 12;
        const float* src = W_out + (size_t)k * Vn + n0 + cq * 4;
        float4 v = *(const float4*)src;
        Bh[cq * 4 + 0][k] = (short)f2bf(v.x);
        Bh[cq * 4 + 1][k] = (short)f2bf(v.y);
        Bh[cq * 4 + 2][k] = (short)f2bf(v.z);
        Bh[cq * 4 + 3][k] = (short)f2bf(v.w);
    }
    __syncthreads();
    int w = tid >> 6, l = tid & 63;
    int lr = l & 15, lk = (l >> 4) * 8;
    float bias[3];
    #pragma unroll
    for (int nt = 0; nt < 3; ++nt) bias[nt] = b_out[n0 + nt * 16 + lr];

    for (int chunk = 0; chunk < 10; ++chunk) {
        int m0 = chunk * 128 + w * 16;
        f32x4 acc[3];
        #pragma unroll
        for (int nt = 0; nt < 3; ++nt) acc[nt] = (f32x4){0.f, 0.f, 0.f, 0.f};
        #pragma unroll 4
        for (int ks = 0; ks < 16; ++ks) {
            int k0 = ks * 32;
            short8 ah = *(const short8*)(Ah + (size_t)(m0 + lr) * DECn + k0 + lk);
            #pragma unroll
            for (int nt = 0; nt < 3; ++nt) {
                short8 bh = *(const short8*)&Bh[nt * 16 + lr][k0 + lk];
                acc[nt] = __builtin_amdgcn_mfma_f32_16x16x32_bf16(ah, bh, acc[nt], 0, 0, 0);
            }
        }
        #pragma unroll
        for (int nt = 0; nt < 3; ++nt) {
            int n = n0 + nt * 16 + lr;
            #pragma unroll
            for (int r = 0; r < 4; ++r) {
                int m = m0 + (l >> 4) * 4 + r;
                out[(size_t)m * Vn + n] = acc[nt][r] + bias[nt];
            }
        }
    }
}

// ================= launcher =================

extern "C" void kernel_launch(void* const* d_in, const int* in_sizes, int n_in,
                              void* d_out, int out_size, void* d_ws, size_t ws_size,
                              hipStream_t stream) {
    const float* features    = (const float*)d_in[0];
    const int*   captions    = (const int*)d_in[1];
    const int*   caption_len = (const int*)d_in[2];
    const float* emb         = (const float*)d_in[3];
    const float* W_enc       = (const float*)d_in[4];
    const float* b_enc       = (const float*)d_in[5];
    const float* W_dec       = (const float*)d_in[6];
    const float* b_dec       = (const float*)d_in[7];
    const float* W_att       = (const float*)d_in[8];
    const float* b_att       = (const float*)d_in[9];
    const float* W_h0        = (const float*)d_in[10];
    const float* b_h0        = (const float*)d_in[11];
    const float* W_c0        = (const float*)d_in[12];
    const float* b_c0        = (const float*)d_in[13];
    const float* W_ih        = (const float*)d_in[14];
    const float* b_ih        = (const float*)d_in[15];
    const float* W_hh        = (const float*)d_in[16];
    const float* b_hh        = (const float*)d_in[17];
    const float* W_out       = (const float*)d_in[18];
    const float* b_out       = (const float*)d_in[19];

    float* out = (float*)d_out;
    float* ws  = (float*)d_ws;

    unsigned short* ws_encproj = (unsigned short*)(ws + WS_ENCPROJ);
    unsigned short* ws_wct     = ws_encproj + (size_t)Bn * Pn * ATTn;  // tail of encproj region
    unsigned short* ws_WT      = (unsigned short*)(ws + WS_WT);        // [2860][2048] bf16
    float* ws_meanf   = ws + WS_CTX;
    float* ws_h0      = ws + WS_H0;
    float* ws_c       = ws + WS_C;
    float* ws_hall    = ws + WS_HALL;
    float* ws_scores  = ws + WS_SCORES;
    short* ws_Ah      = (short*)(ws + WS_ENCPROJ);       // reuse enc_proj region post-loop
    unsigned char* fih = (unsigned char*)out;            // Fih fp8 stash in logits region

    // ---- precompute ----
    k_wct<<<dim3(Gn), 256, 0, stream>>>(W_ih, ws_wct);
    k_transpose_bf<<<dim3((KIH + 31) / 32, Gn / 32), 256, 0, stream>>>(
        W_ih, ws_WT, Gn, KIH);
    k_transpose_bf<<<dim3((DECn + 31) / 32, Gn / 32), 256, 0, stream>>>(
        W_hh, ws_WT + (size_t)KIH * Gn, Gn, DECn);
    k_encproj_mfma<<<dim3(Pn * Bn / 128, ATTn / 128), 256, 0, stream>>>(
        features, W_enc, b_enc, ws_encproj);
    k_fih<<<dim3(Gn / 128, Pn * Bn / 128), 256, 0, stream>>>(features, ws_wct, fih);
    k_mean<<<dim3(Bn, ENCn / 256), 256, 0, stream>>>(features, ws_meanf);
    k_init_state<<<dim3(8, Bn), 256, 0, stream>>>(ws_meanf, W_h0, b_h0, W_c0, b_c0,
                                                  ws_h0, ws_c);
    k_tail<<<dim3((Bn * Tn + Bn + 255) / 256), 256, 0, stream>>>(captions, caption_len, out);

    // ---- recurrence: 2 kernels per step ----
    for (int t = 0; t < STEPSn; ++t) {
        const float* hbase = (t == 0) ? ws_h0 : (ws_hall + (size_t)(t - 1) * DECn);
        int hstride = (t == 0) ? DECn : (STEPSn * DECn);
        k_scores<<<dim3(256), 256, 0, stream>>>(ws_encproj, hbase, hstride,
                                                W_dec, b_dec, W_att, b_att, ws_scores);
        k_gates2<<<dim3(512), 256, 0, stream>>>(ws_WT, fih, emb, captions, ws_scores,
                                                hbase, hstride, b_ih, b_hh,
                                                ws_c, ws_hall, out + OUT_ALPHAS, t);
    }

    // ---- logits: bf16 A, then 1-pass MFMA GEMM (overwrites Fih stash) ----
    k_hall2bf<<<dim3(Bn * STEPSn * DECn / 1024), 256, 0, stream>>>(ws_hall, ws_Ah);
    k_logits_mfma<<<dim3(Vn / 48), 512, 0, stream>>>(ws_Ah, W_out, b_out, out);
}

// Round 17
// 2701.699 us; speedup vs baseline: 1.2241x; 1.0680x over previous
//
#include <hip/hip_runtime.h>
#include <hip/hip_bf16.h>
#include <hip/hip_fp8.h>
#include <cstdint>
#include <cstddef>

// Problem constants
#define Bn 64
#define Pn 196
#define ENCn 2048
#define DECn 512
#define ATTn 512
#define En 300
#define Vn 30000
#define Tn 21
#define STEPSn 20
#define Gn 2048        // 4*DEC gate width
#define KIH 2348       // En + ENCn  (W_ih^T rows)
#define NCAT 2560      // Gn + ATTn  (merged GEMM width)

// ---- workspace layout (float offsets) ----
// encproj REGION (Bn*Pn*ATTn floats = 12,845,056 ushorts) subdivided (ushort offs):
//   [0 .. 6,422,528)            enc_proj bf16 [12544][512]
//   [6,422,528 .. 10,616,832)   WCT bf16 [2048][2048]   (B_cat rows 0..2047)
//   [10,616,832 .. 11,665,408)  W_encT bf16 [512][2048] (B_cat rows 2048..2559)
//   [11,665,408 .. 12,320,768)  hall_bf bf16 [1280][512]
#define WS_ENCPROJ ((size_t)0)
#define WS_WT    (WS_ENCPROJ + (size_t)Bn*Pn*ATTn)        // bf16 [2860][2048] ushort
#define WS_CTX   (WS_WT + (size_t)KIH*Gn)                 // [64][2048] mean_f (pre only)
#define WS_H0    (WS_CTX + (size_t)Bn*ENCn)               // [64][512]
#define WS_C     (WS_H0 + (size_t)Bn*DECn)                // [64][512]
#define WS_HALL  (WS_C + (size_t)Bn*DECn)                 // [64][20][512]
#define WS_SCORES (WS_HALL + (size_t)Bn*STEPSn*DECn)      // [64][196]
#define WS_WDEC  (WS_SCORES + (size_t)Bn*Pn)              // bf16 [512][512] ushort (131,072 floats)

// ---- output layout (float offsets into d_out) ----
#define OUT_ALPHAS ((size_t)Bn*STEPSn*Vn)
#define OUT_CAPT   (OUT_ALPHAS + (size_t)Bn*STEPSn*Pn)
#define OUT_SEQ    (OUT_CAPT + (size_t)Bn*Tn)
// During the loop, d_out bytes [0, 25.7M) hold Fih fp8; [25.7M, 77.1M) hold feat_bf.

typedef __attribute__((ext_vector_type(8))) short short8;
typedef __attribute__((ext_vector_type(4))) short short4v;
typedef __attribute__((ext_vector_type(4))) float f32x4;
typedef __attribute__((ext_vector_type(8))) unsigned char uchar8;

static __device__ __forceinline__ unsigned short f2bf(float f) {
    unsigned u = __float_as_uint(f);
    return (unsigned short)((u + 0x7FFFu + ((u >> 16) & 1u)) >> 16);
}
static __device__ __forceinline__ float bf2f(unsigned short u) {
    return __uint_as_float((unsigned)u << 16);
}
static __device__ __forceinline__ unsigned char f2e4(float f) {
    __hip_fp8_e4m3 v(f);
    return (unsigned char)v.__x;
}
static __device__ __forceinline__ float e42f(unsigned char u) {
    __hip_fp8_e4m3 v;
    v.__x = (__hip_fp8_storage_t)u;
    return (float)v;
}

// ============ merged GEMM: [Fih | enc_proj] = feat_bf @ B_cat^T ============
// A bf16 [12544][2048]; B_cat bf16 [2560][2048] (rows 0..2047 = WCT, 2048.. = W_encT).
// Output n<2048 -> fp8 Fih [m][2048]; n>=2048 -> bf16 enc_proj [m][512] + b_enc.
// Grid 1960 flat; XCD-chunked: x = bid&7, T = x*245 + (bid>>3); m = T/20, n = T%20
// -> each XCD owns ~12 complete m-groups (A-panel fetched once per XCD).
__global__ __launch_bounds__(256) void k_bigemm(const unsigned short* __restrict__ A,
                                                const unsigned short* __restrict__ Bcat,
                                                const float* __restrict__ b_enc,
                                                unsigned char* __restrict__ Cf8,
                                                unsigned short* __restrict__ Cenc) {
    __shared__ short Ahs[128][40];
    __shared__ short Bs[128][40];
    int bid = blockIdx.x;
    int T = (bid & 7) * 245 + (bid >> 3);
    int m0 = (T / 20) * 128, n0 = (T % 20) * 128;
    int tid = threadIdx.x;
    int w = tid >> 6, l = tid & 63;
    int lr = l & 15, lk = (l >> 4) * 8;

    f32x4 acc[2][8];
    #pragma unroll
    for (int mt = 0; mt < 2; ++mt)
        #pragma unroll
        for (int nt = 0; nt < 8; ++nt) acc[mt][nt] = (f32x4){0.f, 0.f, 0.f, 0.f};

    for (int k0 = 0; k0 < ENCn; k0 += 32) {
        __syncthreads();
        #pragma unroll
        for (int i = 0; i < 2; ++i) {
            int q = tid + i * 256;
            int r = q >> 2, c8 = (q & 3) * 8;
            *(short8*)&Ahs[r][c8] =
                *(const short8*)&A[(size_t)(m0 + r) * ENCn + k0 + c8];
        }
        #pragma unroll
        for (int i = 0; i < 2; ++i) {
            int q = tid + i * 256;
            int n = q >> 2, kc = (q & 3) * 8;
            *(short8*)&Bs[n][kc] =
                *(const short8*)&Bcat[(size_t)(n0 + n) * ENCn + k0 + kc];
        }
        __syncthreads();
        short8 ah[2];
        #pragma unroll
        for (int mt = 0; mt < 2; ++mt) {
            int row = w * 32 + mt * 16 + lr;
            ah[mt] = *(const short8*)&Ahs[row][lk];
        }
        #pragma unroll
        for (int nt = 0; nt < 8; ++nt) {
            short8 bs = *(const short8*)&Bs[nt * 16 + lr][lk];
            #pragma unroll
            for (int mt = 0; mt < 2; ++mt) {
                acc[mt][nt] = __builtin_amdgcn_mfma_f32_16x16x32_bf16(ah[mt], bs, acc[mt][nt], 0, 0, 0);
            }
        }
    }
    #pragma unroll
    for (int mt = 0; mt < 2; ++mt) {
        #pragma unroll
        for (int nt = 0; nt < 8; ++nt) {
            int n = n0 + nt * 16 + lr;
            int mb = m0 + w * 32 + mt * 16 + (l >> 4) * 4;
            if (n < Gn) {
                #pragma unroll
                for (int r = 0; r < 4; ++r)
                    Cf8[(size_t)(mb + r) * Gn + n] = f2e4(acc[mt][nt][r]);
            } else {
                int a = n - Gn;
                float bv = b_enc[a];
                #pragma unroll
                for (int r = 0; r < 4; ++r)
                    Cenc[(size_t)(mb + r) * ATTn + a] = f2bf(acc[mt][nt][r] + bv);
            }
        }
    }
}

// ================= small precompute kernels =================

// features fp32 -> bf16 (into d_out stash)
__global__ __launch_bounds__(256) void k_feat2bf(const float* __restrict__ feat,
                                                 unsigned short* __restrict__ outbf) {
    size_t idx = ((size_t)blockIdx.x * 256 + threadIdx.x) * 8;
    float4 v0 = *(const float4*)(feat + idx);
    float4 v1 = *(const float4*)(feat + idx + 4);
    float vv[8] = {v0.x, v0.y, v0.z, v0.w, v1.x, v1.y, v1.z, v1.w};
    short8 o;
    #pragma unroll
    for (int j = 0; j < 8; ++j) o[j] = (short)f2bf(vv[j]);
    *(short8*)(outbf + idx) = o;
}

// flat fp32 -> bf16 (W_dec)
__global__ __launch_bounds__(256) void k_f2bf_flat(const float* __restrict__ in,
                                                   unsigned short* __restrict__ out) {
    size_t idx = ((size_t)blockIdx.x * 256 + threadIdx.x) * 8;
    float4 v0 = *(const float4*)(in + idx);
    float4 v1 = *(const float4*)(in + idx + 4);
    float vv[8] = {v0.x, v0.y, v0.z, v0.w, v1.x, v1.y, v1.z, v1.w};
    short8 o;
    #pragma unroll
    for (int j = 0; j < 8; ++j) o[j] = (short)f2bf(vv[j]);
    *(short8*)(out + idx) = o;
}

// WCT[g][k] = bf16(W_ih[g][En+k])
__global__ __launch_bounds__(256) void k_wct(const float* __restrict__ W_ih,
                                             unsigned short* __restrict__ WCT) {
    int g = blockIdx.x;
    int k8 = threadIdx.x * 8;
    const float* src = W_ih + (size_t)g * KIH + En + k8;
    float4 v0 = *(const float4*)src;
    float4 v1 = *(const float4*)(src + 4);
    float vv[8] = {v0.x, v0.y, v0.z, v0.w, v1.x, v1.y, v1.z, v1.w};
    short8 o;
    #pragma unroll
    for (int j = 0; j < 8; ++j) o[j] = (short)f2bf(vv[j]);
    *(short8*)&WCT[(size_t)g * ENCn + k8] = o;
}

__global__ __launch_bounds__(256) void k_mean(const float* __restrict__ feat,
                                              float* __restrict__ mean_f) {
    int b = blockIdx.x;
    int e = blockIdx.y * 256 + threadIdx.x;
    const float* fb = feat + (size_t)b * Pn * ENCn + e;
    float s = 0.f;
    #pragma unroll 4
    for (int p = 0; p < Pn; ++p) s += fb[(size_t)p * ENCn];
    mean_f[(size_t)b * ENCn + e] = s * (1.0f / (float)Pn);
}

// split-K init (verbatim R16): grid (8, 64)
__global__ __launch_bounds__(256) void k_init_state(
        const float* __restrict__ mf,
        const float* __restrict__ Wh, const float* __restrict__ bh,
        const float* __restrict__ Wc, const float* __restrict__ bc,
        float* __restrict__ h, float* __restrict__ c) {
    __shared__ float mfs[ENCn];
    __shared__ float part[2][4][64];
    int n0 = blockIdx.x * 64;
    int b = blockIdx.y;
    int tid = threadIdx.x;
    int nn = tid & 63, kq = tid >> 6;
    for (int k = tid; k < ENCn; k += 256) mfs[k] = mf[(size_t)b * ENCn + k];
    __syncthreads();
    float ah = 0.f, ac = 0.f;
    int kb = kq * 512;
    #pragma unroll 4
    for (int k = 0; k < 512; ++k) {
        float a = mfs[kb + k];
        ah += a * Wh[(size_t)(kb + k) * DECn + n0 + nn];
        ac += a * Wc[(size_t)(kb + k) * DECn + n0 + nn];
    }
    part[0][kq][nn] = ah;
    part[1][kq][nn] = ac;
    __syncthreads();
    if (tid < 64) {
        float s = bh[n0 + tid] + part[0][0][tid] + part[0][1][tid]
                + part[0][2][tid] + part[0][3][tid];
        h[(size_t)b * DECn + n0 + tid] = s;
    } else if (tid < 128) {
        int n2 = tid - 64;
        float s = bc[n0 + n2] + part[1][0][n2] + part[1][1][n2]
                + part[1][2][n2] + part[1][3][n2];
        c[(size_t)b * DECn + n0 + n2] = s;
    }
}

// transpose in[R][C] fp32 -> out[C][R] bf16
__global__ __launch_bounds__(256) void k_transpose_bf(const float* __restrict__ in,
                                                      unsigned short* __restrict__ out,
                                                      int R, int C) {
    __shared__ float tile[32][33];
    int c0 = blockIdx.x * 32, r0 = blockIdx.y * 32;
    int tx = threadIdx.x & 31, ty = threadIdx.x >> 5;
    for (int i = ty; i < 32; i += 8) {
        int r = r0 + i, cc = c0 + tx;
        tile[i][tx] = (r < R && cc < C) ? in[(size_t)r * C + cc] : 0.f;
    }
    __syncthreads();
    for (int i = ty; i < 32; i += 8) {
        int cc = c0 + i, r = r0 + tx;
        if (cc < C && r < R) out[(size_t)cc * R + r] = f2bf(tile[tx][i]);
    }
}

__global__ __launch_bounds__(256) void k_tail(const int* __restrict__ captions,
                                              const int* __restrict__ caption_len,
                                              float* __restrict__ out) {
    int i = blockIdx.x * 256 + threadIdx.x;
    if (i < Bn * Tn) {
        out[OUT_CAPT + i] = (float)captions[i];
    } else if (i < Bn * Tn + Bn) {
        int b = i - Bn * Tn;
        out[OUT_SEQ + b] = (float)(caption_len[b] - 1);
    }
}

// ================= per-step kernel A: hdec + raw scores (bf16 W_dec) =================
__global__ __launch_bounds__(256) void k_scores(const unsigned short* __restrict__ enc_proj,
                                                const float* __restrict__ hbase, int hstride,
                                                const unsigned short* __restrict__ Wdec_bf,
                                                const float* __restrict__ b_dec,
                                                const float* __restrict__ W_att,
                                                const float* __restrict__ b_att,
                                                float* __restrict__ scores) {
    __shared__ float hv[DECn];
    __shared__ float hs[ATTn];
    __shared__ float wa[ATTn];
    int bid = blockIdx.x;
    int b = bid >> 2, q = bid & 3;
    int tid = threadIdx.x;
    hv[tid]       = hbase[(size_t)b * hstride + tid];
    hv[tid + 256] = hbase[(size_t)b * hstride + tid + 256];
    wa[tid]       = W_att[tid];
    wa[tid + 256] = W_att[tid + 256];
    __syncthreads();
    {
        float acc0 = b_dec[tid], acc1 = b_dec[tid + 256];
        const unsigned short* wd = Wdec_bf + tid;
        #pragma unroll 8
        for (int k = 0; k < DECn; ++k) {
            float h = hv[k];
            acc0 += h * bf2f(wd[(size_t)k * DECn]);
            acc1 += h * bf2f(wd[(size_t)k * DECn + 256]);
        }
        hs[tid] = acc0;
        hs[tid + 256] = acc1;
    }
    __syncthreads();
    int wv = tid >> 6, lane = tid & 63;
    float batt = b_att[0];
    for (int p = q * 49 + wv; p < q * 49 + 49; p += 4) {
        const unsigned short* ep = enc_proj + ((size_t)b * Pn + p) * ATTn;
        float s = 0.f;
        #pragma unroll
        for (int a = lane; a < ATTn; a += 64) {
            float v = bf2f(ep[a]) + hs[a];
            s += fmaxf(v, 0.f) * wa[a];
        }
        #pragma unroll
        for (int off = 32; off > 0; off >>= 1) s += __shfl_xor(s, off);
        if (lane == 0) scores[(size_t)b * Pn + p] = s + batt;
    }
}

// ================= per-step kernel B: softmax + gates + LSTM (fp8 Fih) =================
// 512 blocks: b = bid>>3, ds = bid&7. g = (tid>>6)*512 + ds*64 + (tid&63).
// Also writes hall_bf (bf16) for the final logits GEMM.
__global__ __launch_bounds__(256) void k_gates2(const unsigned short* __restrict__ WT,
                                                const unsigned char* __restrict__ Fih,
                                                const float* __restrict__ emb,
                                                const int* __restrict__ captions,
                                                const float* __restrict__ scores,
                                                const float* __restrict__ hbase, int hstride,
                                                const float* __restrict__ b_ih,
                                                const float* __restrict__ b_hh,
                                                float* __restrict__ c,
                                                float* __restrict__ hall,
                                                unsigned short* __restrict__ hall_bf,
                                                float* __restrict__ alphas_out, int t) {
    __shared__ float al[Pn];
    __shared__ float red[4];
    __shared__ float Aemb[En];
    __shared__ float Ah2[DECn];
    __shared__ unsigned char Ftile[48][256];
    __shared__ float sg[4][64];
    int bid = blockIdx.x;
    int b = bid >> 3, ds = bid & 7;
    int tid = threadIdx.x;
    int gate = tid >> 6, dd = tid & 63;
    int g = (gate << 9) + ds * 64 + dd;

    // softmax (redundant per ds)
    int wv = tid >> 6, lane = tid & 63;
    float v = (tid < Pn) ? scores[(size_t)b * Pn + tid] : -1e30f;
    float m = v;
    #pragma unroll
    for (int off = 32; off > 0; off >>= 1) m = fmaxf(m, __shfl_xor(m, off));
    if (lane == 0) red[wv] = m;
    __syncthreads();
    float M = fmaxf(fmaxf(red[0], red[1]), fmaxf(red[2], red[3]));
    __syncthreads();
    float e = (tid < Pn) ? expf(v - M) : 0.f;
    float s = e;
    #pragma unroll
    for (int off = 32; off > 0; off >>= 1) s += __shfl_xor(s, off);
    if (lane == 0) red[wv] = s;
    __syncthreads();
    float S = red[0] + red[1] + red[2] + red[3];
    float an = e / S;
    if (tid < Pn) {
        al[tid] = an;
        if (ds == 0) alphas_out[((size_t)b * STEPSn + t) * Pn + tid] = an;
    }
    // stage emb + h
    const float* er = emb + (size_t)captions[b * Tn + t] * En;
    for (int k = tid; k < En; k += 256) Aemb[k] = er[k];
    for (int k = tid; k < DECn; k += 256) Ah2[k] = hbase[(size_t)b * hstride + k];
    __syncthreads();

    const unsigned char* fb = Fih + (size_t)b * Pn * Gn;
    auto ldF = [&](int p0_, int q) -> uchar8 {
        int pr = q >> 5, j = q & 31;
        int seg = j >> 3, s8 = (j & 7) * 8;
        return *(const uchar8*)&fb[(size_t)(p0_ + pr) * Gn + ((seg << 9) + ds * 64 + s8)];
    };
    auto stF = [&](int q, uchar8 vv8) {
        int pr = q >> 5, j = q & 31;
        int seg = j >> 3, s8 = (j & 7) * 8;
        *(uchar8*)&Ftile[pr][seg * 64 + s8] = vv8;
    };

    float acc = b_ih[g] + b_hh[g];

    uchar8 r0 = ldF(0, tid);
    uchar8 r1 = ldF(0, tid + 256);
    uchar8 r2 = ldF(0, tid + 512);
    uchar8 r3 = ldF(0, tid + 768);
    uchar8 r4 = ldF(0, tid + 1024);
    uchar8 r5 = ldF(0, tid + 1280);

    #pragma unroll 4
    for (int k = 0; k < En; ++k)
        acc += Aemb[k] * bf2f(WT[(size_t)k * Gn + g]);

    int p0 = 0;
    #pragma unroll
    for (int pc = 0; pc < 4; ++pc) {
        __syncthreads();
        stF(tid, r0); stF(tid + 256, r1); stF(tid + 512, r2);
        stF(tid + 768, r3); stF(tid + 1024, r4); stF(tid + 1280, r5);
        __syncthreads();
        if (pc < 3) {
            int np = p0 + 48;
            r0 = ldF(np, tid); r1 = ldF(np, tid + 256); r2 = ldF(np, tid + 512);
            r3 = ldF(np, tid + 768); r4 = ldF(np, tid + 1024); r5 = ldF(np, tid + 1280);
        } else if (tid < 128) {
            r0 = ldF(p0 + 48, tid);
        }
        #pragma unroll 4
        for (int pr = 0; pr < 48; ++pr)
            acc += al[p0 + pr] * e42f(Ftile[pr][tid]);
        p0 += 48;
    }
    __syncthreads();
    if (tid < 128) stF(tid, r0);
    __syncthreads();
    #pragma unroll
    for (int pr = 0; pr < 4; ++pr)
        acc += al[p0 + pr] * e42f(Ftile[pr][tid]);

    #pragma unroll 4
    for (int k = 0; k < DECn; ++k)
        acc += Ah2[k] * bf2f(WT[(size_t)(KIH + k) * Gn + g]);

    sg[gate][dd] = acc;
    __syncthreads();
    if (tid < 64) {
        float gi = sg[0][tid], gf = sg[1][tid];
        float gg = sg[2][tid], go = sg[3][tid];
        int d = ds * 64 + tid;
        float si = 1.f / (1.f + expf(-gi));
        float sf = 1.f / (1.f + expf(-gf));
        float so = 1.f / (1.f + expf(-go));
        size_t cidx = (size_t)b * DECn + d;
        float cc = sf * c[cidx] + si * tanhf(gg);
        float hh = so * tanhf(cc);
        c[cidx] = cc;
        size_t hidx = ((size_t)b * STEPSn + t) * DECn + d;
        hall[hidx] = hh;
        hall_bf[hidx] = f2bf(hh);
    }
}

// ================= logits: 1-pass bf16 MFMA (reads hall_bf) =================

__global__ __launch_bounds__(512) void k_logits_mfma(const unsigned short* __restrict__ Ah,
                                                     const float* __restrict__ W_out,
                                                     const float* __restrict__ b_out,
                                                     float* __restrict__ out) {
    __shared__ short Bh[48][520];
    int n0 = blockIdx.x * 48;
    int tid = threadIdx.x;
    for (int q = tid; q < 6144; q += 512) {
        int cq = q % 12, k = q / 12;
        const float* src = W_out + (size_t)k * Vn + n0 + cq * 4;
        float4 v = *(const float4*)src;
        Bh[cq * 4 + 0][k] = (short)f2bf(v.x);
        Bh[cq * 4 + 1][k] = (short)f2bf(v.y);
        Bh[cq * 4 + 2][k] = (short)f2bf(v.z);
        Bh[cq * 4 + 3][k] = (short)f2bf(v.w);
    }
    __syncthreads();
    int w = tid >> 6, l = tid & 63;
    int lr = l & 15, lk = (l >> 4) * 8;
    float bias[3];
    #pragma unroll
    for (int nt = 0; nt < 3; ++nt) bias[nt] = b_out[n0 + nt * 16 + lr];

    for (int chunk = 0; chunk < 10; ++chunk) {
        int m0 = chunk * 128 + w * 16;
        f32x4 acc[3];
        #pragma unroll
        for (int nt = 0; nt < 3; ++nt) acc[nt] = (f32x4){0.f, 0.f, 0.f, 0.f};
        #pragma unroll 4
        for (int ks = 0; ks < 16; ++ks) {
            int k0 = ks * 32;
            short8 ah = *(const short8*)(Ah + (size_t)(m0 + lr) * DECn + k0 + lk);
            #pragma unroll
            for (int nt = 0; nt < 3; ++nt) {
                short8 bh = *(const short8*)&Bh[nt * 16 + lr][k0 + lk];
                acc[nt] = __builtin_amdgcn_mfma_f32_16x16x32_bf16(ah, bh, acc[nt], 0, 0, 0);
            }
        }
        #pragma unroll
        for (int nt = 0; nt < 3; ++nt) {
            int n = n0 + nt * 16 + lr;
            #pragma unroll
            for (int r = 0; r < 4; ++r) {
                int m = m0 + (l >> 4) * 4 + r;
                out[(size_t)m * Vn + n] = acc[nt][r] + bias[nt];
            }
        }
    }
}

// ================= launcher =================

extern "C" void kernel_launch(void* const* d_in, const int* in_sizes, int n_in,
                              void* d_out, int out_size, void* d_ws, size_t ws_size,
                              hipStream_t stream) {
    const float* features    = (const float*)d_in[0];
    const int*   captions    = (const int*)d_in[1];
    const int*   caption_len = (const int*)d_in[2];
    const float* emb         = (const float*)d_in[3];
    const float* W_enc       = (const float*)d_in[4];
    const float* b_enc       = (const float*)d_in[5];
    const float* W_dec       = (const float*)d_in[6];
    const float* b_dec       = (const float*)d_in[7];
    const float* W_att       = (const float*)d_in[8];
    const float* b_att       = (const float*)d_in[9];
    const float* W_h0        = (const float*)d_in[10];
    const float* b_h0        = (const float*)d_in[11];
    const float* W_c0        = (const float*)d_in[12];
    const float* b_c0        = (const float*)d_in[13];
    const float* W_ih        = (const float*)d_in[14];
    const float* b_ih        = (const float*)d_in[15];
    const float* W_hh        = (const float*)d_in[16];
    const float* b_hh        = (const float*)d_in[17];
    const float* W_out       = (const float*)d_in[18];
    const float* b_out       = (const float*)d_in[19];

    float* out = (float*)d_out;
    float* ws  = (float*)d_ws;

    unsigned short* ws_encproj = (unsigned short*)(ws + WS_ENCPROJ);
    unsigned short* ws_wct     = ws_encproj + (size_t)Bn * Pn * ATTn;
    unsigned short* ws_wencT   = ws_wct + (size_t)Gn * ENCn;
    unsigned short* ws_hallbf  = ws_wencT + (size_t)ATTn * ENCn;
    unsigned short* ws_WT      = (unsigned short*)(ws + WS_WT);
    float* ws_meanf   = ws + WS_CTX;
    float* ws_h0      = ws + WS_H0;
    float* ws_c       = ws + WS_C;
    float* ws_hall    = ws + WS_HALL;
    float* ws_scores  = ws + WS_SCORES;
    unsigned short* ws_wdec = (unsigned short*)(ws + WS_WDEC);
    unsigned char* fih = (unsigned char*)out;                    // fp8 Fih [12544][2048]
    unsigned short* feat_bf = (unsigned short*)(fih + (size_t)Bn * Pn * Gn);  // bf16 features

    // ---- precompute ----
    k_feat2bf<<<dim3(Bn * Pn * ENCn / 2048), 256, 0, stream>>>(features, feat_bf);
    k_wct<<<dim3(Gn), 256, 0, stream>>>(W_ih, ws_wct);
    k_transpose_bf<<<dim3((ENCn + 31) / 32, ATTn / 32), 256, 0, stream>>>(
        W_enc, ws_wencT, ENCn, ATTn);                            // W_enc [2048][512] -> [512][2048]
    k_transpose_bf<<<dim3((KIH + 31) / 32, Gn / 32), 256, 0, stream>>>(
        W_ih, ws_WT, Gn, KIH);
    k_transpose_bf<<<dim3((DECn + 31) / 32, Gn / 32), 256, 0, stream>>>(
        W_hh, ws_WT + (size_t)KIH * Gn, Gn, DECn);
    k_f2bf_flat<<<dim3(DECn * DECn / 2048), 256, 0, stream>>>(W_dec, ws_wdec);
    k_bigemm<<<dim3(8 * 245), 256, 0, stream>>>(feat_bf, ws_wct, b_enc, fih, ws_encproj);
    k_mean<<<dim3(Bn, ENCn / 256), 256, 0, stream>>>(features, ws_meanf);
    k_init_state<<<dim3(8, Bn), 256, 0, stream>>>(ws_meanf, W_h0, b_h0, W_c0, b_c0,
                                                  ws_h0, ws_c);
    k_tail<<<dim3((Bn * Tn + Bn + 255) / 256), 256, 0, stream>>>(captions, caption_len, out);

    // ---- recurrence: 2 kernels per step ----
    for (int t = 0; t < STEPSn; ++t) {
        const float* hbase = (t == 0) ? ws_h0 : (ws_hall + (size_t)(t - 1) * DECn);
        int hstride = (t == 0) ? DECn : (STEPSn * DECn);
        k_scores<<<dim3(256), 256, 0, stream>>>(ws_encproj, hbase, hstride,
                                                ws_wdec, b_dec, W_att, b_att, ws_scores);
        k_gates2<<<dim3(512), 256, 0, stream>>>(ws_WT, fih, emb, captions, ws_scores,
                                                hbase, hstride, b_ih, b_hh,
                                                ws_c, ws_hall, ws_hallbf,
                                                out + OUT_ALPHAS, t);
    }

    // ---- logits: 1-pass MFMA GEMM from hall_bf (overwrites Fih/feat_bf stash) ----
    k_logits_mfma<<<dim3(Vn / 48), 512, 0, stream>>>(ws_hallbf, W_out, b_out, out);
}

// Round 18
// 1782.459 us; speedup vs baseline: 1.8553x; 1.5157x over previous
//
#include <hip/hip_runtime.h>
#include <hip/hip_bf16.h>
#include <hip/hip_fp8.h>
#include <cstdint>
#include <cstddef>

// Problem constants
#define Bn 64
#define Pn 196
#define ENCn 2048
#define DECn 512
#define ATTn 512
#define En 300
#define Vn 30000
#define Tn 21
#define STEPSn 20
#define Gn 2048        // 4*DEC gate width
#define KIH 2348       // En + ENCn  (W_ih^T rows)

// ---- workspace layout (float offsets) ----
#define WS_ENCPROJ ((size_t)0)
#define WS_WT    (WS_ENCPROJ + (size_t)Bn*Pn*ATTn)        // bf16 [2860][2048] ushort
#define WS_CTX   (WS_WT + (size_t)KIH*Gn)                 // [64][2048] mean_f (pre only)
#define WS_H0    (WS_CTX + (size_t)Bn*ENCn)               // [64][512]
#define WS_C     (WS_H0 + (size_t)Bn*DECn)                // [64][512]
#define WS_HALL  (WS_C + (size_t)Bn*DECn)                 // [64][20][512]
#define WS_SCORES (WS_HALL + (size_t)Bn*STEPSn*DECn)      // [64][196]
#define WS_WDEC  (WS_SCORES + (size_t)Bn*Pn)              // bf16 [512][512] ushort

// ---- output layout (float offsets into d_out) ----
#define OUT_ALPHAS ((size_t)Bn*STEPSn*Vn)
#define OUT_CAPT   (OUT_ALPHAS + (size_t)Bn*STEPSn*Pn)
#define OUT_SEQ    (OUT_CAPT + (size_t)Bn*Tn)
// d_out stash bytes: [0,25.69M) Fih fp8; [25.69M,77.07M) feat_bf; [77.07M,107.8M) W_out bf16.

typedef __attribute__((ext_vector_type(8))) short short8;
typedef __attribute__((ext_vector_type(4))) short short4v;
typedef __attribute__((ext_vector_type(4))) float f32x4;
typedef __attribute__((ext_vector_type(8))) unsigned char uchar8;

static __device__ __forceinline__ unsigned short f2bf(float f) {
    unsigned u = __float_as_uint(f);
    return (unsigned short)((u + 0x7FFFu + ((u >> 16) & 1u)) >> 16);
}
static __device__ __forceinline__ float bf2f(unsigned short u) {
    return __uint_as_float((unsigned)u << 16);
}
static __device__ __forceinline__ unsigned char f2e4(float f) {
    __hip_fp8_e4m3 v(f);
    return (unsigned char)v.__x;
}
static __device__ __forceinline__ float e42f(unsigned char u) {
    __hip_fp8_e4m3 v;
    v.__x = (__hip_fp8_storage_t)u;
    return (float)v;
}

// ============ merged GEMM: [Fih | enc_proj] = feat_bf @ B_cat^T (verbatim R17) ============
__global__ __launch_bounds__(256) void k_bigemm(const unsigned short* __restrict__ A,
                                                const unsigned short* __restrict__ Bcat,
                                                const float* __restrict__ b_enc,
                                                unsigned char* __restrict__ Cf8,
                                                unsigned short* __restrict__ Cenc) {
    __shared__ short Ahs[128][40];
    __shared__ short Bs[128][40];
    int bid = blockIdx.x;
    int T = (bid & 7) * 245 + (bid >> 3);
    int m0 = (T / 20) * 128, n0 = (T % 20) * 128;
    int tid = threadIdx.x;
    int w = tid >> 6, l = tid & 63;
    int lr = l & 15, lk = (l >> 4) * 8;

    f32x4 acc[2][8];
    #pragma unroll
    for (int mt = 0; mt < 2; ++mt)
        #pragma unroll
        for (int nt = 0; nt < 8; ++nt) acc[mt][nt] = (f32x4){0.f, 0.f, 0.f, 0.f};

    for (int k0 = 0; k0 < ENCn; k0 += 32) {
        __syncthreads();
        #pragma unroll
        for (int i = 0; i < 2; ++i) {
            int q = tid + i * 256;
            int r = q >> 2, c8 = (q & 3) * 8;
            *(short8*)&Ahs[r][c8] =
                *(const short8*)&A[(size_t)(m0 + r) * ENCn + k0 + c8];
        }
        #pragma unroll
        for (int i = 0; i < 2; ++i) {
            int q = tid + i * 256;
            int n = q >> 2, kc = (q & 3) * 8;
            *(short8*)&Bs[n][kc] =
                *(const short8*)&Bcat[(size_t)(n0 + n) * ENCn + k0 + kc];
        }
        __syncthreads();
        short8 ah[2];
        #pragma unroll
        for (int mt = 0; mt < 2; ++mt) {
            int row = w * 32 + mt * 16 + lr;
            ah[mt] = *(const short8*)&Ahs[row][lk];
        }
        #pragma unroll
        for (int nt = 0; nt < 8; ++nt) {
            short8 bs = *(const short8*)&Bs[nt * 16 + lr][lk];
            #pragma unroll
            for (int mt = 0; mt < 2; ++mt) {
                acc[mt][nt] = __builtin_amdgcn_mfma_f32_16x16x32_bf16(ah[mt], bs, acc[mt][nt], 0, 0, 0);
            }
        }
    }
    #pragma unroll
    for (int mt = 0; mt < 2; ++mt) {
        #pragma unroll
        for (int nt = 0; nt < 8; ++nt) {
            int n = n0 + nt * 16 + lr;
            int mb = m0 + w * 32 + mt * 16 + (l >> 4) * 4;
            if (n < Gn) {
                #pragma unroll
                for (int r = 0; r < 4; ++r)
                    Cf8[(size_t)(mb + r) * Gn + n] = f2e4(acc[mt][nt][r]);
            } else {
                int a = n - Gn;
                float bv = b_enc[a];
                #pragma unroll
                for (int r = 0; r < 4; ++r)
                    Cenc[(size_t)(mb + r) * ATTn + a] = f2bf(acc[mt][nt][r] + bv);
            }
        }
    }
}

// ================= small precompute kernels =================

__global__ __launch_bounds__(256) void k_feat2bf(const float* __restrict__ feat,
                                                 unsigned short* __restrict__ outbf) {
    size_t idx = ((size_t)blockIdx.x * 256 + threadIdx.x) * 8;
    float4 v0 = *(const float4*)(feat + idx);
    float4 v1 = *(const float4*)(feat + idx + 4);
    float vv[8] = {v0.x, v0.y, v0.z, v0.w, v1.x, v1.y, v1.z, v1.w};
    short8 o;
    #pragma unroll
    for (int j = 0; j < 8; ++j) o[j] = (short)f2bf(vv[j]);
    *(short8*)(outbf + idx) = o;
}

__global__ __launch_bounds__(256) void k_f2bf_flat(const float* __restrict__ in,
                                                   unsigned short* __restrict__ out) {
    size_t idx = ((size_t)blockIdx.x * 256 + threadIdx.x) * 8;
    float4 v0 = *(const float4*)(in + idx);
    float4 v1 = *(const float4*)(in + idx + 4);
    float vv[8] = {v0.x, v0.y, v0.z, v0.w, v1.x, v1.y, v1.z, v1.w};
    short8 o;
    #pragma unroll
    for (int j = 0; j < 8; ++j) o[j] = (short)f2bf(vv[j]);
    *(short8*)(out + idx) = o;
}

__global__ __launch_bounds__(256) void k_wct(const float* __restrict__ W_ih,
                                             unsigned short* __restrict__ WCT) {
    int g = blockIdx.x;
    int k8 = threadIdx.x * 8;
    const float* src = W_ih + (size_t)g * KIH + En + k8;
    float4 v0 = *(const float4*)src;
    float4 v1 = *(const float4*)(src + 4);
    float vv[8] = {v0.x, v0.y, v0.z, v0.w, v1.x, v1.y, v1.z, v1.w};
    short8 o;
    #pragma unroll
    for (int j = 0; j < 8; ++j) o[j] = (short)f2bf(vv[j]);
    *(short8*)&WCT[(size_t)g * ENCn + k8] = o;
}

__global__ __launch_bounds__(256) void k_mean(const float* __restrict__ feat,
                                              float* __restrict__ mean_f) {
    int b = blockIdx.x;
    int e = blockIdx.y * 256 + threadIdx.x;
    const float* fb = feat + (size_t)b * Pn * ENCn + e;
    float s = 0.f;
    #pragma unroll 4
    for (int p = 0; p < Pn; ++p) s += fb[(size_t)p * ENCn];
    mean_f[(size_t)b * ENCn + e] = s * (1.0f / (float)Pn);
}

__global__ __launch_bounds__(256) void k_init_state(
        const float* __restrict__ mf,
        const float* __restrict__ Wh, const float* __restrict__ bh,
        const float* __restrict__ Wc, const float* __restrict__ bc,
        float* __restrict__ h, float* __restrict__ c) {
    __shared__ float mfs[ENCn];
    __shared__ float part[2][4][64];
    int n0 = blockIdx.x * 64;
    int b = blockIdx.y;
    int tid = threadIdx.x;
    int nn = tid & 63, kq = tid >> 6;
    for (int k = tid; k < ENCn; k += 256) mfs[k] = mf[(size_t)b * ENCn + k];
    __syncthreads();
    float ah = 0.f, ac = 0.f;
    int kb = kq * 512;
    #pragma unroll 4
    for (int k = 0; k < 512; ++k) {
        float a = mfs[kb + k];
        ah += a * Wh[(size_t)(kb + k) * DECn + n0 + nn];
        ac += a * Wc[(size_t)(kb + k) * DECn + n0 + nn];
    }
    part[0][kq][nn] = ah;
    part[1][kq][nn] = ac;
    __syncthreads();
    if (tid < 64) {
        float s = bh[n0 + tid] + part[0][0][tid] + part[0][1][tid]
                + part[0][2][tid] + part[0][3][tid];
        h[(size_t)b * DECn + n0 + tid] = s;
    } else if (tid < 128) {
        int n2 = tid - 64;
        float s = bc[n0 + n2] + part[1][0][n2] + part[1][1][n2]
                + part[1][2][n2] + part[1][3][n2];
        c[(size_t)b * DECn + n0 + n2] = s;
    }
}

__global__ __launch_bounds__(256) void k_transpose_bf(const float* __restrict__ in,
                                                      unsigned short* __restrict__ out,
                                                      int R, int C) {
    __shared__ float tile[32][33];
    int c0 = blockIdx.x * 32, r0 = blockIdx.y * 32;
    int tx = threadIdx.x & 31, ty = threadIdx.x >> 5;
    for (int i = ty; i < 32; i += 8) {
        int r = r0 + i, cc = c0 + tx;
        tile[i][tx] = (r < R && cc < C) ? in[(size_t)r * C + cc] : 0.f;
    }
    __syncthreads();
    for (int i = ty; i < 32; i += 8) {
        int cc = c0 + i, r = r0 + tx;
        if (cc < C && r < R) out[(size_t)cc * R + r] = f2bf(tile[tx][i]);
    }
}

__global__ __launch_bounds__(256) void k_tail(const int* __restrict__ captions,
                                              const int* __restrict__ caption_len,
                                              float* __restrict__ out) {
    int i = blockIdx.x * 256 + threadIdx.x;
    if (i < Bn * Tn) {
        out[OUT_CAPT + i] = (float)captions[i];
    } else if (i < Bn * Tn + Bn) {
        int b = i - Bn * Tn;
        out[OUT_SEQ + b] = (float)(caption_len[b] - 1);
    }
}

// ================= per-step kernel A: hdec + raw scores (verbatim R17) =================
__global__ __launch_bounds__(256) void k_scores(const unsigned short* __restrict__ enc_proj,
                                                const float* __restrict__ hbase, int hstride,
                                                const unsigned short* __restrict__ Wdec_bf,
                                                const float* __restrict__ b_dec,
                                                const float* __restrict__ W_att,
                                                const float* __restrict__ b_att,
                                                float* __restrict__ scores) {
    __shared__ float hv[DECn];
    __shared__ float hs[ATTn];
    __shared__ float wa[ATTn];
    int bid = blockIdx.x;
    int b = bid >> 2, q = bid & 3;
    int tid = threadIdx.x;
    hv[tid]       = hbase[(size_t)b * hstride + tid];
    hv[tid + 256] = hbase[(size_t)b * hstride + tid + 256];
    wa[tid]       = W_att[tid];
    wa[tid + 256] = W_att[tid + 256];
    __syncthreads();
    {
        float acc0 = b_dec[tid], acc1 = b_dec[tid + 256];
        const unsigned short* wd = Wdec_bf + tid;
        #pragma unroll 8
        for (int k = 0; k < DECn; ++k) {
            float h = hv[k];
            acc0 += h * bf2f(wd[(size_t)k * DECn]);
            acc1 += h * bf2f(wd[(size_t)k * DECn + 256]);
        }
        hs[tid] = acc0;
        hs[tid + 256] = acc1;
    }
    __syncthreads();
    int wv = tid >> 6, lane = tid & 63;
    float batt = b_att[0];
    for (int p = q * 49 + wv; p < q * 49 + 49; p += 4) {
        const unsigned short* ep = enc_proj + ((size_t)b * Pn + p) * ATTn;
        float s = 0.f;
        #pragma unroll
        for (int a = lane; a < ATTn; a += 64) {
            float v = bf2f(ep[a]) + hs[a];
            s += fmaxf(v, 0.f) * wa[a];
        }
        #pragma unroll
        for (int off = 32; off > 0; off >>= 1) s += __shfl_xor(s, off);
        if (lane == 0) scores[(size_t)b * Pn + p] = s + batt;
    }
}

// ================= per-step kernel B: softmax + gates + LSTM =================
// 512 blocks: b = bid>>3, ds = bid&7. g = (tid>>6)*512 + ds*64 + (tid&63).
// WT emb/h slices staged via LDS in 32-row chunks (reg-prefetch); Fih via fp8 LDS
// chunks (verbatim R17). MAC values & order bit-identical to R17.
__global__ __launch_bounds__(256) void k_gates2(const unsigned short* __restrict__ WT,
                                                const unsigned char* __restrict__ Fih,
                                                const float* __restrict__ emb,
                                                const int* __restrict__ captions,
                                                const float* __restrict__ scores,
                                                const float* __restrict__ hbase, int hstride,
                                                const float* __restrict__ b_ih,
                                                const float* __restrict__ b_hh,
                                                float* __restrict__ c,
                                                float* __restrict__ hall,
                                                unsigned short* __restrict__ hall_bf,
                                                float* __restrict__ alphas_out, int t) {
    __shared__ float al[Pn];
    __shared__ float red[4];
    __shared__ float Aemb[En];
    __shared__ float Ah2[DECn];
    __shared__ __align__(16) unsigned char uni[16384];   // Wl[32][256]us ∪ Ftile[48][256]u8
    __shared__ float sg[4][64];
    unsigned short (*Wl)[256] = (unsigned short (*)[256])uni;
    unsigned char (*Ftile)[256] = (unsigned char (*)[256])uni;
    int bid = blockIdx.x;
    int b = bid >> 3, ds = bid & 7;
    int tid = threadIdx.x;
    int gate = tid >> 6, dd = tid & 63;
    int g = (gate << 9) + ds * 64 + dd;

    // softmax (redundant per ds)
    int wv = tid >> 6, lane = tid & 63;
    float v = (tid < Pn) ? scores[(size_t)b * Pn + tid] : -1e30f;
    float m = v;
    #pragma unroll
    for (int off = 32; off > 0; off >>= 1) m = fmaxf(m, __shfl_xor(m, off));
    if (lane == 0) red[wv] = m;
    __syncthreads();
    float M = fmaxf(fmaxf(red[0], red[1]), fmaxf(red[2], red[3]));
    __syncthreads();
    float e = (tid < Pn) ? expf(v - M) : 0.f;
    float s = e;
    #pragma unroll
    for (int off = 32; off > 0; off >>= 1) s += __shfl_xor(s, off);
    if (lane == 0) red[wv] = s;
    __syncthreads();
    float S = red[0] + red[1] + red[2] + red[3];
    float an = e / S;
    if (tid < Pn) {
        al[tid] = an;
        if (ds == 0) alphas_out[((size_t)b * STEPSn + t) * Pn + tid] = an;
    }
    // stage emb + h
    const float* er = emb + (size_t)captions[b * Tn + t] * En;
    for (int k = tid; k < En; k += 256) Aemb[k] = er[k];
    for (int k = tid; k < DECn; k += 256) Ah2[k] = hbase[(size_t)b * hstride + k];
    __syncthreads();

    const unsigned char* fb = Fih + (size_t)b * Pn * Gn;
    auto ldF = [&](int p0_, int q) -> uchar8 {
        int pr = q >> 5, j = q & 31;
        int seg = j >> 3, s8 = (j & 7) * 8;
        return *(const uchar8*)&fb[(size_t)(p0_ + pr) * Gn + ((seg << 9) + ds * 64 + s8)];
    };
    auto stF = [&](int q, uchar8 vv8) {
        int pr = q >> 5, j = q & 31;
        int seg = j >> 3, s8 = (j & 7) * 8;
        *(uchar8*)&Ftile[pr][seg * 64 + s8] = vv8;
    };
    auto ldW = [&](int kbase, int q) -> short8 {
        int r = q >> 5, c8 = q & 31;
        int seg = c8 >> 3, j8 = (c8 & 7) * 8;
        return *(const short8*)&WT[(size_t)(kbase + r) * Gn + ((seg << 9) + ds * 64 + j8)];
    };
    auto stW = [&](int q, short8 v8) {
        int r = q >> 5, c8 = q & 31;
        int seg = c8 >> 3, j8 = (c8 & 7) * 8;
        *(short8*)&Wl[r][seg * 64 + j8] = v8;
    };

    float acc = b_ih[g] + b_hh[g];

    // issue Fih chunk-0 loads early (hide under emb phase)
    uchar8 r0 = ldF(0, tid);
    uchar8 r1 = ldF(0, tid + 256);
    uchar8 r2 = ldF(0, tid + 512);
    uchar8 r3 = ldF(0, tid + 768);
    uchar8 r4 = ldF(0, tid + 1024);
    uchar8 r5 = ldF(0, tid + 1280);

    // ---- emb part: 9 chunks of 32 + tail 12 (k ascending, LDS-staged) ----
    {
        short8 w0 = ldW(0, tid), w1 = ldW(0, tid + 256);
        short8 w2 = ldW(0, tid + 512), w3 = ldW(0, tid + 768);
        for (int ch = 0; ch < 9; ++ch) {
            int kb = ch * 32;
            __syncthreads();
            stW(tid, w0); stW(tid + 256, w1); stW(tid + 512, w2); stW(tid + 768, w3);
            __syncthreads();
            if (ch < 8) {
                int nb = kb + 32;
                w0 = ldW(nb, tid); w1 = ldW(nb, tid + 256);
                w2 = ldW(nb, tid + 512); w3 = ldW(nb, tid + 768);
            } else {
                w0 = ldW(288, tid);                      // tail rows 12: tasks 384
                if (tid < 128) w1 = ldW(288, tid + 256);
            }
            #pragma unroll 4
            for (int r = 0; r < 32; ++r)
                acc += Aemb[kb + r] * bf2f(Wl[r][tid]);
        }
        __syncthreads();
        stW(tid, w0);
        if (tid < 128) stW(tid + 256, w1);
        __syncthreads();
        #pragma unroll
        for (int r = 0; r < 12; ++r)
            acc += Aemb[288 + r] * bf2f(Wl[r][tid]);
    }

    // ---- Fih part: 4 chunks of 48 + tail 4 (verbatim R17 pattern) ----
    int p0 = 0;
    #pragma unroll
    for (int pc = 0; pc < 4; ++pc) {
        __syncthreads();
        stF(tid, r0); stF(tid + 256, r1); stF(tid + 512, r2);
        stF(tid + 768, r3); stF(tid + 1024, r4); stF(tid + 1280, r5);
        __syncthreads();
        if (pc < 3) {
            int np = p0 + 48;
            r0 = ldF(np, tid); r1 = ldF(np, tid + 256); r2 = ldF(np, tid + 512);
            r3 = ldF(np, tid + 768); r4 = ldF(np, tid + 1024); r5 = ldF(np, tid + 1280);
        } else if (tid < 128) {
            r0 = ldF(p0 + 48, tid);
        }
        #pragma unroll 4
        for (int pr = 0; pr < 48; ++pr)
            acc += al[p0 + pr] * e42f(Ftile[pr][tid]);
        p0 += 48;
    }
    __syncthreads();
    if (tid < 128) stF(tid, r0);
    __syncthreads();
    #pragma unroll
    for (int pr = 0; pr < 4; ++pr)
        acc += al[p0 + pr] * e42f(Ftile[pr][tid]);

    // ---- h part: 16 chunks of 32 (k ascending, LDS-staged) ----
    {
        short8 w0 = ldW(KIH, tid), w1 = ldW(KIH, tid + 256);
        short8 w2 = ldW(KIH, tid + 512), w3 = ldW(KIH, tid + 768);
        for (int ch = 0; ch < 16; ++ch) {
            int kb = ch * 32;
            __syncthreads();
            stW(tid, w0); stW(tid + 256, w1); stW(tid + 512, w2); stW(tid + 768, w3);
            __syncthreads();
            if (ch < 15) {
                int nb = KIH + kb + 32;
                w0 = ldW(nb, tid); w1 = ldW(nb, tid + 256);
                w2 = ldW(nb, tid + 512); w3 = ldW(nb, tid + 768);
            }
            #pragma unroll 4
            for (int r = 0; r < 32; ++r)
                acc += Ah2[kb + r] * bf2f(Wl[r][tid]);
        }
    }

    sg[gate][dd] = acc;
    __syncthreads();
    if (tid < 64) {
        float gi = sg[0][tid], gf = sg[1][tid];
        float gg = sg[2][tid], go = sg[3][tid];
        int d = ds * 64 + tid;
        float si = 1.f / (1.f + expf(-gi));
        float sf = 1.f / (1.f + expf(-gf));
        float so = 1.f / (1.f + expf(-go));
        size_t cidx = (size_t)b * DECn + d;
        float cc = sf * c[cidx] + si * tanhf(gg);
        float hh = so * tanhf(cc);
        c[cidx] = cc;
        size_t hidx = ((size_t)b * STEPSn + t) * DECn + d;
        hall[hidx] = hh;
        hall_bf[hidx] = f2bf(hh);
    }
}

// ================= logits: 1-pass bf16 MFMA (B pre-converted) =================

__global__ __launch_bounds__(512) void k_logits_mfma(const unsigned short* __restrict__ Ah,
                                                     const unsigned short* __restrict__ Wb,
                                                     const float* __restrict__ b_out,
                                                     float* __restrict__ out) {
    __shared__ short Bh[48][520];
    int n0 = blockIdx.x * 48;
    int tid = threadIdx.x;
    for (int q = tid; q < 3072; q += 512) {
        int cq = q % 6, k = q / 6;
        short8 v8 = *(const short8*)&Wb[(size_t)k * Vn + n0 + cq * 8];
        #pragma unroll
        for (int j = 0; j < 8; ++j) Bh[cq * 8 + j][k] = v8[j];
    }
    __syncthreads();
    int w = tid >> 6, l = tid & 63;
    int lr = l & 15, lk = (l >> 4) * 8;
    float bias[3];
    #pragma unroll
    for (int nt = 0; nt < 3; ++nt) bias[nt] = b_out[n0 + nt * 16 + lr];

    for (int chunk = 0; chunk < 10; ++chunk) {
        int m0 = chunk * 128 + w * 16;
        f32x4 acc[3];
        #pragma unroll
        for (int nt = 0; nt < 3; ++nt) acc[nt] = (f32x4){0.f, 0.f, 0.f, 0.f};
        #pragma unroll 4
        for (int ks = 0; ks < 16; ++ks) {
            int k0 = ks * 32;
            short8 ah = *(const short8*)(Ah + (size_t)(m0 + lr) * DECn + k0 + lk);
            #pragma unroll
            for (int nt = 0; nt < 3; ++nt) {
                short8 bh = *(const short8*)&Bh[nt * 16 + lr][k0 + lk];
                acc[nt] = __builtin_amdgcn_mfma_f32_16x16x32_bf16(ah, bh, acc[nt], 0, 0, 0);
            }
        }
        #pragma unroll
        for (int nt = 0; nt < 3; ++nt) {
            int n = n0 + nt * 16 + lr;
            #pragma unroll
            for (int r = 0; r < 4; ++r) {
                int m = m0 + (l >> 4) * 4 + r;
                out[(size_t)m * Vn + n] = acc[nt][r] + bias[nt];
            }
        }
    }
}

// ================= launcher =================

extern "C" void kernel_launch(void* const* d_in, const int* in_sizes, int n_in,
                              void* d_out, int out_size, void* d_ws, size_t ws_size,
                              hipStream_t stream) {
    const float* features    = (const float*)d_in[0];
    const int*   captions    = (const int*)d_in[1];
    const int*   caption_len = (const int*)d_in[2];
    const float* emb         = (const float*)d_in[3];
    const float* W_enc       = (const float*)d_in[4];
    const float* b_enc       = (const float*)d_in[5];
    const float* W_dec       = (const float*)d_in[6];
    const float* b_dec       = (const float*)d_in[7];
    const float* W_att       = (const float*)d_in[8];
    const float* b_att       = (const float*)d_in[9];
    const float* W_h0        = (const float*)d_in[10];
    const float* b_h0        = (const float*)d_in[11];
    const float* W_c0        = (const float*)d_in[12];
    const float* b_c0        = (const float*)d_in[13];
    const float* W_ih        = (const float*)d_in[14];
    const float* b_ih        = (const float*)d_in[15];
    const float* W_hh        = (const float*)d_in[16];
    const float* b_hh        = (const float*)d_in[17];
    const float* W_out       = (const float*)d_in[18];
    const float* b_out       = (const float*)d_in[19];

    float* out = (float*)d_out;
    float* ws  = (float*)d_ws;

    unsigned short* ws_encproj = (unsigned short*)(ws + WS_ENCPROJ);
    unsigned short* ws_wct     = ws_encproj + (size_t)Bn * Pn * ATTn;
    unsigned short* ws_wencT   = ws_wct + (size_t)Gn * ENCn;
    unsigned short* ws_hallbf  = ws_wencT + (size_t)ATTn * ENCn;
    unsigned short* ws_WT      = (unsigned short*)(ws + WS_WT);
    float* ws_meanf   = ws + WS_CTX;
    float* ws_h0      = ws + WS_H0;
    float* ws_c       = ws + WS_C;
    float* ws_hall    = ws + WS_HALL;
    float* ws_scores  = ws + WS_SCORES;
    unsigned short* ws_wdec = (unsigned short*)(ws + WS_WDEC);
    unsigned char* fih = (unsigned char*)out;                               // fp8 [12544][2048]
    unsigned short* feat_bf = (unsigned short*)(fih + (size_t)Bn * Pn * Gn);
    unsigned short* wout_bf = feat_bf + (size_t)Bn * Pn * ENCn;             // bf16 [512][30000]

    // ---- precompute ----
    k_feat2bf<<<dim3(Bn * Pn * ENCn / 2048), 256, 0, stream>>>(features, feat_bf);
    k_wct<<<dim3(Gn), 256, 0, stream>>>(W_ih, ws_wct);
    k_transpose_bf<<<dim3((ENCn + 31) / 32, ATTn / 32), 256, 0, stream>>>(
        W_enc, ws_wencT, ENCn, ATTn);
    k_transpose_bf<<<dim3((KIH + 31) / 32, Gn / 32), 256, 0, stream>>>(
        W_ih, ws_WT, Gn, KIH);
    k_transpose_bf<<<dim3((DECn + 31) / 32, Gn / 32), 256, 0, stream>>>(
        W_hh, ws_WT + (size_t)KIH * Gn, Gn, DECn);
    k_f2bf_flat<<<dim3(DECn * DECn / 2048), 256, 0, stream>>>(W_dec, ws_wdec);
    k_f2bf_flat<<<dim3((int)((size_t)DECn * Vn / 2048)), 256, 0, stream>>>(W_out, wout_bf);
    k_bigemm<<<dim3(8 * 245), 256, 0, stream>>>(feat_bf, ws_wct, b_enc, fih, ws_encproj);
    k_mean<<<dim3(Bn, ENCn / 256), 256, 0, stream>>>(features, ws_meanf);
    k_init_state<<<dim3(8, Bn), 256, 0, stream>>>(ws_meanf, W_h0, b_h0, W_c0, b_c0,
                                                  ws_h0, ws_c);
    k_tail<<<dim3((Bn * Tn + Bn + 255) / 256), 256, 0, stream>>>(captions, caption_len, out);

    // ---- recurrence: 2 kernels per step ----
    for (int t = 0; t < STEPSn; ++t) {
        const float* hbase = (t == 0) ? ws_h0 : (ws_hall + (size_t)(t - 1) * DECn);
        int hstride = (t == 0) ? DECn : (STEPSn * DECn);
        k_scores<<<dim3(256), 256, 0, stream>>>(ws_encproj, hbase, hstride,
                                                ws_wdec, b_dec, W_att, b_att, ws_scores);
        k_gates2<<<dim3(512), 256, 0, stream>>>(ws_WT, fih, emb, captions, ws_scores,
                                                hbase, hstride, b_ih, b_hh,
                                                ws_c, ws_hall, ws_hallbf,
                                                out + OUT_ALPHAS, t);
    }

    // ---- logits: 1-pass MFMA GEMM from hall_bf + pre-converted W_out ----
    k_logits_mfma<<<dim3(Vn / 48), 512, 0, stream>>>(ws_hallbf, wout_bf, b_out, out);
}